// Round 11
// baseline (539.487 us; speedup 1.0000x reference)
//
#include <hip/hip_runtime.h>
#include <stdint.h>

// Problem constants (B=4, S=1024, H=2048, NH=16, HD=128)
#define HDIM 2048
#define SEQLEN 1024
#define NHEADS 16
#define HEADD 128

typedef unsigned short u16;
typedef unsigned int u32;
typedef __attribute__((ext_vector_type(8))) short bf16x8;   // MFMA A/B frag
typedef __attribute__((ext_vector_type(8))) u16 u16x8;
typedef __attribute__((ext_vector_type(4))) u16 u16x4;
typedef __attribute__((ext_vector_type(4))) float f32x4;

__device__ __forceinline__ float bf2f(u16 u) {
    union { u32 i; float f; } v; v.i = ((u32)u) << 16; return v.f;
}
__device__ __forceinline__ u16 f2bf(float f) {
    union { float f; u32 i; } v; v.f = f;
    return (u16)((v.i + 0x7fffu + ((v.i >> 16) & 1u)) >> 16);  // RNE
}
__device__ __forceinline__ float silu_f(float x) {
    return x / (1.f + __expf(-x));
}
// Async global->LDS, 16B per lane. LDS dest = wave-uniform base + lane*16.
__device__ __forceinline__ void glds16(const void* g, void* l) {
    __builtin_amdgcn_global_load_lds(
        (const __attribute__((address_space(1))) u32*)g,
        (__attribute__((address_space(3))) u32*)l, 16, 0, 0);
}

// ---------------------------------------------------------------------------
// f32 -> bf16 bulk convert (8 elems/thread/iter), n8 = n/8.
__global__ __launch_bounds__(256) void f32_to_bf16(const float* __restrict__ in,
                                                   u16* __restrict__ out, int n8) {
    int i = blockIdx.x * 256 + threadIdx.x;
    const int stride = gridDim.x * 256;
    for (; i < n8; i += stride) {
        f32x4 a = *(const f32x4*)&in[(size_t)i * 8];
        f32x4 b = *(const f32x4*)&in[(size_t)i * 8 + 4];
        u16x8 o;
#pragma unroll
        for (int j = 0; j < 4; ++j) { o[j] = f2bf(a[j]); o[4 + j] = f2bf(b[j]); }
        *(u16x8*)&out[(size_t)i * 8] = o;
    }
}

// ---------------------------------------------------------------------------
// Transpose + downconvert W[k][n] (2048x2048 f32) -> WT[n][k] bf16.
__global__ __launch_bounds__(256) void transpose_w(const float* __restrict__ W,
                                                   u16* __restrict__ WT) {
    __shared__ u16 T[64][72];
    const int r0 = blockIdx.y * 64;   // k
    const int c0 = blockIdx.x * 64;   // n
    const int t = threadIdx.x;
#pragma unroll
    for (int c = t; c < 1024; c += 256) {
        const int r = c >> 4, cc = (c & 15) << 2;
        f32x4 v = *(const f32x4*)&W[(size_t)(r0 + r) * HDIM + c0 + cc];
        u16x4 o;
#pragma unroll
        for (int j = 0; j < 4; ++j) o[j] = f2bf(v[j]);
        *(u16x4*)&T[r][cc] = o;
    }
    __syncthreads();
#pragma unroll
    for (int c = t; c < 512; c += 256) {
        const int n = c & 63, kc = (c >> 6) << 3;
        u16x8 v;
#pragma unroll
        for (int j = 0; j < 8; ++j) v[j] = T[kc + j][n];
        *(u16x8*)&WT[(size_t)(c0 + n) * HDIM + r0 + kc] = v;
    }
}

// ---------------------------------------------------------------------------
// Transpose V: Vbuf[b*1024+s][h*128+d] bf16 -> VTg[(bh*128+d)*1024+s] bf16.
__global__ __launch_bounds__(256) void transpose_v(const u16* __restrict__ V,
                                                   u16* __restrict__ VT) {
    __shared__ u16 T[64][72];
    const int bh = blockIdx.y;
    const int st = (blockIdx.x & 15) * 64;
    const int dt = (blockIdx.x >> 4) * 64;
    const int b = bh >> 4, h = bh & 15;
    const int t = threadIdx.x;
#pragma unroll
    for (int c = t; c < 512; c += 256) {
        const int s = c >> 3, d8 = (c & 7) << 3;
        *(u16x8*)&T[s][d8] =
            *(const u16x8*)&V[(size_t)(b * SEQLEN + st + s) * HDIM + h * HEADD + dt + d8];
    }
    __syncthreads();
#pragma unroll
    for (int c = t; c < 512; c += 256) {
        const int d = c & 63, s8 = (c >> 6) << 3;
        u16x8 v;
#pragma unroll
        for (int j = 0; j < 8; ++j) v[j] = T[s8 + j][d];
        *(u16x8*)&VT[((size_t)bh * HEADD + dt + d) * SEQLEN + st + s8] = v;
    }
}

// ---------------------------------------------------------------------------
// Pipelined GEMM (unchanged): BM=256 x BN=128, BK=64, 8 waves.
__global__ __launch_bounds__(512) void gemm256(
    const u16* __restrict__ X, const u16* __restrict__ WT,
    const float* __restrict__ bias, void* __restrict__ outp, const int mode)
{
    extern __shared__ u16 lds[];   // 2 bufs x (A 16384 + B 8192) u16 = 96 KiB
    const int t = threadIdx.x;
    const int lane = t & 63, wid = t >> 6;
    const int l15 = lane & 15, l4 = lane >> 4;
    const int wr = wid >> 2, wn = wid & 3;

    const int bid = blockIdx.x;
    const int u = (bid & 7) * 32 + (bid >> 3);
    const int tm = u & 15, tn = u >> 4;
    const int m0 = tm * 256, n0 = tn * 128;

    const int ric = t >> 3;
    const int cse = (((t & 7) ^ (ric & 7)) << 3);
    const u16* gA = X  + (size_t)(m0 + ric) * HDIM + cse;
    const u16* gB = WT + (size_t)(n0 + ric) * HDIM + cse;

    u16* buf0 = lds;
    u16* buf1 = lds + 24576;
    const int wbase = wid * 512;

    int offA[8][2], offB[2][2];
#pragma unroll
    for (int mf = 0; mf < 8; ++mf) {
        const int row = wr * 128 + mf * 16 + l15;
#pragma unroll
        for (int kk = 0; kk < 2; ++kk)
            offA[mf][kk] = ((row * 128 + kk * 64 + l4 * 16) ^ ((row & 7) << 4)) >> 1;
    }
#pragma unroll
    for (int nf = 0; nf < 2; ++nf) {
        const int row = wn * 32 + nf * 16 + l15;
#pragma unroll
        for (int kk = 0; kk < 2; ++kk)
            offB[nf][kk] = 16384 + (((row * 128 + kk * 64 + l4 * 16) ^ ((row & 7) << 4)) >> 1);
    }

#define STAGE_A(buf, c, kt) glds16(gA + (size_t)(c) * 64 * HDIM + (kt) * 64, (buf) + (c) * 4096 + wbase)
#define STAGE_B(buf, c, kt) glds16(gB + (size_t)(c) * 64 * HDIM + (kt) * 64, (buf) + 16384 + (c) * 4096 + wbase)

    STAGE_B(buf0, 0, 0); STAGE_B(buf0, 1, 0);
    STAGE_A(buf0, 0, 0); STAGE_A(buf0, 1, 0); STAGE_A(buf0, 2, 0); STAGE_A(buf0, 3, 0);
    STAGE_B(buf1, 0, 1); STAGE_B(buf1, 1, 1);
    STAGE_A(buf1, 0, 1); STAGE_A(buf1, 2, 1);
    asm volatile("s_waitcnt vmcnt(4)" ::: "memory");
    __builtin_amdgcn_s_barrier();

    f32x4 acc[8][2] = {};
    u16* pc = buf0;
    u16* pn = buf1;

#pragma unroll 1
    for (int tt = 0; tt < 32; ++tt) {
        bf16x8 bfr[2][2], afr[4][2];
#pragma unroll
        for (int nf = 0; nf < 2; ++nf)
#pragma unroll
            for (int kk = 0; kk < 2; ++kk)
                bfr[nf][kk] = *(const bf16x8*)(pc + offB[nf][kk]);
#pragma unroll
        for (int mf = 0; mf < 4; ++mf)
#pragma unroll
            for (int kk = 0; kk < 2; ++kk)
                afr[mf][kk] = *(const bf16x8*)(pc + offA[mf][kk]);
        if (tt + 1 < 32) { STAGE_A(pn, 1, tt + 1); STAGE_A(pn, 3, tt + 1); }
        __builtin_amdgcn_s_barrier();
        asm volatile("s_waitcnt lgkmcnt(0)");
        __builtin_amdgcn_sched_barrier(0);
        __builtin_amdgcn_s_setprio(1);
#pragma unroll
        for (int mf = 0; mf < 4; ++mf)
#pragma unroll
            for (int nf = 0; nf < 2; ++nf)
#pragma unroll
                for (int kk = 0; kk < 2; ++kk)
                    acc[mf][nf] = __builtin_amdgcn_mfma_f32_16x16x32_bf16(
                        afr[mf][kk], bfr[nf][kk], acc[mf][nf], 0, 0, 0);
        __builtin_amdgcn_s_setprio(0);
        __builtin_amdgcn_s_barrier();

#pragma unroll
        for (int mf = 0; mf < 4; ++mf)
#pragma unroll
            for (int kk = 0; kk < 2; ++kk)
                afr[mf][kk] = *(const bf16x8*)(pc + offA[4 + mf][kk]);
        if (tt + 2 < 32) {
            STAGE_B(pc, 0, tt + 2); STAGE_B(pc, 1, tt + 2);
            STAGE_A(pc, 0, tt + 2); STAGE_A(pc, 2, tt + 2);
        }
        __builtin_amdgcn_s_barrier();
        asm volatile("s_waitcnt lgkmcnt(0)");
        __builtin_amdgcn_sched_barrier(0);
        __builtin_amdgcn_s_setprio(1);
#pragma unroll
        for (int mf = 0; mf < 4; ++mf)
#pragma unroll
            for (int nf = 0; nf < 2; ++nf)
#pragma unroll
                for (int kk = 0; kk < 2; ++kk)
                    acc[4 + mf][nf] = __builtin_amdgcn_mfma_f32_16x16x32_bf16(
                        afr[mf][kk], bfr[nf][kk], acc[4 + mf][nf], 0, 0, 0);
        __builtin_amdgcn_s_setprio(0);
        if (tt + 2 < 32)      { asm volatile("s_waitcnt vmcnt(4)" ::: "memory"); }
        else if (tt + 1 < 32) { asm volatile("s_waitcnt vmcnt(0)" ::: "memory"); }
        __builtin_amdgcn_s_barrier();
        u16* tmp = pc; pc = pn; pn = tmp;
    }
#undef STAGE_A
#undef STAGE_B

#pragma unroll
    for (int nf = 0; nf < 2; ++nf) {
        const int n = n0 + wn * 32 + nf * 16 + l15;
        const float bv = bias[n];
#pragma unroll
        for (int mf = 0; mf < 8; ++mf) {
            const int mb = m0 + wr * 128 + mf * 16 + (l4 << 2);
#pragma unroll
            for (int r = 0; r < 4; ++r) {
                const float v = acc[mf][nf][r] + bv;
                if (mode == 0)
                    ((u16*)outp)[(size_t)(mb + r) * HDIM + n] = f2bf(silu_f(v));
                else
                    ((float*)outp)[(size_t)(mb + r) * HDIM + n] = v;
            }
        }
    }
}

// ---------------------------------------------------------------------------
// Fused SiLU-attention + gating, barrier-free k-loop, 64 q-rows/block
// (wave = 16 q-rows).  Grid 1024 = 4 blocks/CU for TLP; K/V^T fragments read
// directly from L2 (bh%8 XCD keying -> ~4MB/XCD working set).
// LDS: Ps [64][72] + relh[1024] = 13.3 KB.
__global__ __launch_bounds__(256) void attn_fused(
    const u16* __restrict__ Qb, const u16* __restrict__ Kb,
    const u16* __restrict__ VTg, const u16* __restrict__ Ub,
    const float* __restrict__ rel, u16* __restrict__ G)
{
    __shared__ u16 Ps[64 * 72];
    __shared__ float relh[1024];

    // Decode: XCD = idx%8 = bh%8; qt interleaved short/long for balance.
    const int idx = blockIdx.x;
    const int bh8 = idx & 7;
    const int rest = idx >> 3;            // 0..127
    const int qraw = rest & 15;
    const int bhhi = rest >> 4;           // 0..7
    const int bh = bhhi * 8 + bh8;
    const int qt = (qraw & 1) ? (15 - (qraw >> 1)) : (qraw >> 1);
    const int b = bh >> 4, h = bh & 15;
    const int qb0 = qt * 64;
    const int t = threadIdx.x, lane = t & 63, w = t >> 6;
    const int l15 = lane & 15, l4 = lane >> 4;
    const size_t rowbase = (size_t)b * SEQLEN;
    const int col0 = h * HEADD;
    const float scale = 0.088388347648318447f;   // 1/sqrt(128)

    for (int i = t; i < 1024; i += 256) relh[i] = rel[(size_t)(1023 + i) * NHEADS + h];

    // Q A-frags in registers (wave's 16 q-rows)
    const int qrow = qb0 + w * 16 + l15;
    bf16x8 aq[4];
#pragma unroll
    for (int dc = 0; dc < 4; ++dc)
        aq[dc] = *(const bf16x8*)&Qb[(rowbase + qrow) * HDIM + col0 + dc * 32 + (l4 << 3)];
    __syncthreads();   // relh visible to all waves

    // Per-lane global bases for K / V^T fragment reads
    const u16* gK = Kb + (rowbase + l15) * HDIM + col0 + (l4 << 3);
    const u16* gV = VTg + ((size_t)bh * HEADD + l15) * SEQLEN + (l4 << 3);

    f32x4 oacc[8] = {};
    const int nkt = qt + 1;
    u16* Pw = Ps + w * 16 * 72;           // wave-private P slice [16][72]

#pragma unroll 1
    for (int kt = 0; kt < nkt; ++kt) {
        const int k0 = kt * 64;

        // QK^T + rel + causal mask + silu -> Pw (K frags straight from L2)
#pragma unroll
        for (int kf = 0; kf < 4; ++kf) {
            f32x4 s = {};
#pragma unroll
            for (int dc = 0; dc < 4; ++dc) {
                bf16x8 bk = *(const bf16x8*)(gK + (size_t)(k0 + kf * 16) * HDIM + dc * 32);
                s = __builtin_amdgcn_mfma_f32_16x16x32_bf16(aq[dc], bk, s, 0, 0, 0);
            }
            const int kabs = k0 + kf * 16 + l15;
#pragma unroll
            for (int r = 0; r < 4; ++r) {
                const int qabs = qb0 + w * 16 + (l4 << 2) + r;
                float v = 0.f;
                if (kabs <= qabs) {
                    const float sc = s[r] * scale + relh[qabs - kabs];
                    v = silu_f(sc);
                }
                Pw[((l4 << 2) + r) * 72 + kf * 16 + l15] = f2bf(v);
            }
        }

        // PV: O[16q][128d] += P[16q][64k] @ V[64k][128d]; V^T frags from L2.
        bf16x8 ap[2];
#pragma unroll
        for (int kc = 0; kc < 2; ++kc)
            ap[kc] = *(const bf16x8*)&Pw[l15 * 72 + kc * 32 + (l4 << 3)];
#pragma unroll
        for (int df = 0; df < 8; ++df) {
#pragma unroll
            for (int kc = 0; kc < 2; ++kc) {
                bf16x8 bv = *(const bf16x8*)(gV + (size_t)df * 16 * SEQLEN + k0 + kc * 32);
                oacc[df] = __builtin_amdgcn_mfma_f32_16x16x32_bf16(ap[kc], bv, oacc[df], 0, 0, 0);
            }
        }
    }

    // G = O * U
#pragma unroll
    for (int df = 0; df < 8; ++df) {
        const int d = df * 16 + l15;
#pragma unroll
        for (int r = 0; r < 4; ++r) {
            const int qabs = qb0 + w * 16 + (l4 << 2) + r;
            const size_t ga = (rowbase + qabs) * HDIM + col0 + d;
            G[ga] = f2bf(oacc[df][r] * bf2f(Ub[ga]));
        }
    }
}

// ---------------------------------------------------------------------------
extern "C" void kernel_launch(void* const* d_in, const int* in_sizes, int n_in,
                              void* d_out, int out_size, void* d_ws, size_t ws_size,
                              hipStream_t stream) {
    const float* query = (const float*)d_in[0];
    const float* key_  = (const float*)d_in[1];
    const float* value = (const float*)d_in[2];
    // d_in[3] attn_mask: causal by construction, handled analytically.
    const float* Wq  = (const float*)d_in[4];  const float* bq  = (const float*)d_in[5];
    const float* Wk  = (const float*)d_in[6];  const float* bk  = (const float*)d_in[7];
    const float* Wv  = (const float*)d_in[8];  const float* bv  = (const float*)d_in[9];
    const float* Wu  = (const float*)d_in[10]; const float* bu  = (const float*)d_in[11];
    const float* Wf2 = (const float*)d_in[12]; const float* bf2 = (const float*)d_in[13];
    const float* rel = (const float*)d_in[14];

    // Workspace (88 MiB): WT 8 | Xbf 16 | Q(=G) 16 | K 16 | V 16 | U 16
    char* ws = (char*)d_ws;
    const size_t WBYTES = (size_t)HDIM * HDIM * 2;   // 8 MiB
    const size_t ABYTES = (size_t)4096 * HDIM * 2;   // 16 MiB
    u16* WT   = (u16*)ws;
    u16* Xbf  = (u16*)(ws + WBYTES);
    u16* Qbuf = (u16*)(ws + WBYTES + 1 * ABYTES);
    u16* Kbuf = (u16*)(ws + WBYTES + 2 * ABYTES);
    u16* Vbuf = (u16*)(ws + WBYTES + 3 * ABYTES);
    u16* Ubuf = (u16*)(ws + WBYTES + 4 * ABYTES);
    u16* Gbuf = Qbuf;          // attn reads its own Q rows, then writes them as G
    u16* VTg  = Xbf;           // free after V GEMM; reused for transposed V

    dim3 tpb(256);
    dim3 tgrid(32, 32);        // W transpose tiles
    dim3 vgrid(32, 64);        // V transpose
    const int n8 = 4096 * HDIM / 8;
    const size_t GLDS = 98304; // 96 KiB dynamic LDS for gemm256

    f32_to_bf16<<<2048, tpb, 0, stream>>>(query, Xbf, n8);
    transpose_w<<<tgrid, tpb, 0, stream>>>(Wq, WT);
    gemm256<<<256, 512, GLDS, stream>>>(Xbf, WT, bq, Qbuf, 0);
    transpose_w<<<tgrid, tpb, 0, stream>>>(Wu, WT);
    gemm256<<<256, 512, GLDS, stream>>>(Xbf, WT, bu, Ubuf, 0);
    f32_to_bf16<<<2048, tpb, 0, stream>>>(key_, Xbf, n8);
    transpose_w<<<tgrid, tpb, 0, stream>>>(Wk, WT);
    gemm256<<<256, 512, GLDS, stream>>>(Xbf, WT, bk, Kbuf, 0);
    f32_to_bf16<<<2048, tpb, 0, stream>>>(value, Xbf, n8);
    transpose_w<<<tgrid, tpb, 0, stream>>>(Wv, WT);
    gemm256<<<256, 512, GLDS, stream>>>(Xbf, WT, bv, Vbuf, 0);
    transpose_v<<<vgrid, tpb, 0, stream>>>(Vbuf, VTg);
    attn_fused<<<1024, tpb, 0, stream>>>(Qbuf, Kbuf, VTg, Ubuf, rel, Gbuf);
    transpose_w<<<tgrid, tpb, 0, stream>>>(Wf2, WT);
    gemm256<<<256, 512, GLDS, stream>>>(Gbuf, WT, bf2, d_out, 1);
}

// Round 12
// 395.952 us; speedup vs baseline: 1.3625x; 1.3625x over previous
//
#include <hip/hip_runtime.h>
#include <stdint.h>

// Problem constants (B=4, S=1024, H=2048, NH=16, HD=128)
#define HDIM 2048
#define SEQLEN 1024
#define NHEADS 16
#define HEADD 128

typedef unsigned short u16;
typedef unsigned int u32;
typedef __attribute__((ext_vector_type(8))) short bf16x8;   // MFMA A/B frag
typedef __attribute__((ext_vector_type(8))) u16 u16x8;
typedef __attribute__((ext_vector_type(4))) u16 u16x4;
typedef __attribute__((ext_vector_type(4))) float f32x4;

__device__ __forceinline__ float bf2f(u16 u) {
    union { u32 i; float f; } v; v.i = ((u32)u) << 16; return v.f;
}
__device__ __forceinline__ u16 f2bf(float f) {
    union { float f; u32 i; } v; v.f = f;
    return (u16)((v.i + 0x7fffu + ((v.i >> 16) & 1u)) >> 16);  // RNE
}
__device__ __forceinline__ float silu_f(float x) {
    return x / (1.f + __expf(-x));
}
// Async global->LDS, 16B per lane. LDS dest = wave-uniform base + lane*16.
__device__ __forceinline__ void glds16(const void* g, void* l) {
    __builtin_amdgcn_global_load_lds(
        (const __attribute__((address_space(1))) u32*)g,
        (__attribute__((address_space(3))) u32*)l, 16, 0, 0);
}

// ---------------------------------------------------------------------------
// f32 -> bf16 bulk convert (8 elems/thread/iter), n8 = n/8.
__global__ __launch_bounds__(256) void f32_to_bf16(const float* __restrict__ in,
                                                   u16* __restrict__ out, int n8) {
    int i = blockIdx.x * 256 + threadIdx.x;
    const int stride = gridDim.x * 256;
    for (; i < n8; i += stride) {
        f32x4 a = *(const f32x4*)&in[(size_t)i * 8];
        f32x4 b = *(const f32x4*)&in[(size_t)i * 8 + 4];
        u16x8 o;
#pragma unroll
        for (int j = 0; j < 4; ++j) { o[j] = f2bf(a[j]); o[4 + j] = f2bf(b[j]); }
        *(u16x8*)&out[(size_t)i * 8] = o;
    }
}

// ---------------------------------------------------------------------------
// Transpose + downconvert W[k][n] (2048x2048 f32) -> WT[n][k] bf16.
__global__ __launch_bounds__(256) void transpose_w(const float* __restrict__ W,
                                                   u16* __restrict__ WT) {
    __shared__ u16 T[64][72];
    const int r0 = blockIdx.y * 64;   // k
    const int c0 = blockIdx.x * 64;   // n
    const int t = threadIdx.x;
#pragma unroll
    for (int c = t; c < 1024; c += 256) {
        const int r = c >> 4, cc = (c & 15) << 2;
        f32x4 v = *(const f32x4*)&W[(size_t)(r0 + r) * HDIM + c0 + cc];
        u16x4 o;
#pragma unroll
        for (int j = 0; j < 4; ++j) o[j] = f2bf(v[j]);
        *(u16x4*)&T[r][cc] = o;
    }
    __syncthreads();
#pragma unroll
    for (int c = t; c < 512; c += 256) {
        const int n = c & 63, kc = (c >> 6) << 3;
        u16x8 v;
#pragma unroll
        for (int j = 0; j < 8; ++j) v[j] = T[kc + j][n];
        *(u16x8*)&WT[(size_t)(c0 + n) * HDIM + r0 + kc] = v;
    }
}

// ---------------------------------------------------------------------------
// Transpose V: Vbuf[b*1024+s][h*128+d] bf16 -> VTg[(bh*128+d)*1024+s] bf16.
__global__ __launch_bounds__(256) void transpose_v(const u16* __restrict__ V,
                                                   u16* __restrict__ VT) {
    __shared__ u16 T[64][72];
    const int bh = blockIdx.y;
    const int st = (blockIdx.x & 15) * 64;
    const int dt = (blockIdx.x >> 4) * 64;
    const int b = bh >> 4, h = bh & 15;
    const int t = threadIdx.x;
#pragma unroll
    for (int c = t; c < 512; c += 256) {
        const int s = c >> 3, d8 = (c & 7) << 3;
        *(u16x8*)&T[s][d8] =
            *(const u16x8*)&V[(size_t)(b * SEQLEN + st + s) * HDIM + h * HEADD + dt + d8];
    }
    __syncthreads();
#pragma unroll
    for (int c = t; c < 512; c += 256) {
        const int d = c & 63, s8 = (c >> 6) << 3;
        u16x8 v;
#pragma unroll
        for (int j = 0; j < 8; ++j) v[j] = T[s8 + j][d];
        *(u16x8*)&VT[((size_t)bh * HEADD + dt + d) * SEQLEN + st + s8] = v;
    }
}

// ---------------------------------------------------------------------------
// Pipelined GEMM (unchanged): BM=256 x BN=128, BK=64, 8 waves.
__global__ __launch_bounds__(512) void gemm256(
    const u16* __restrict__ X, const u16* __restrict__ WT,
    const float* __restrict__ bias, void* __restrict__ outp, const int mode)
{
    extern __shared__ u16 lds[];   // 2 bufs x (A 16384 + B 8192) u16 = 96 KiB
    const int t = threadIdx.x;
    const int lane = t & 63, wid = t >> 6;
    const int l15 = lane & 15, l4 = lane >> 4;
    const int wr = wid >> 2, wn = wid & 3;

    const int bid = blockIdx.x;
    const int u = (bid & 7) * 32 + (bid >> 3);
    const int tm = u & 15, tn = u >> 4;
    const int m0 = tm * 256, n0 = tn * 128;

    const int ric = t >> 3;
    const int cse = (((t & 7) ^ (ric & 7)) << 3);
    const u16* gA = X  + (size_t)(m0 + ric) * HDIM + cse;
    const u16* gB = WT + (size_t)(n0 + ric) * HDIM + cse;

    u16* buf0 = lds;
    u16* buf1 = lds + 24576;
    const int wbase = wid * 512;

    int offA[8][2], offB[2][2];
#pragma unroll
    for (int mf = 0; mf < 8; ++mf) {
        const int row = wr * 128 + mf * 16 + l15;
#pragma unroll
        for (int kk = 0; kk < 2; ++kk)
            offA[mf][kk] = ((row * 128 + kk * 64 + l4 * 16) ^ ((row & 7) << 4)) >> 1;
    }
#pragma unroll
    for (int nf = 0; nf < 2; ++nf) {
        const int row = wn * 32 + nf * 16 + l15;
#pragma unroll
        for (int kk = 0; kk < 2; ++kk)
            offB[nf][kk] = 16384 + (((row * 128 + kk * 64 + l4 * 16) ^ ((row & 7) << 4)) >> 1);
    }

#define STAGE_A(buf, c, kt) glds16(gA + (size_t)(c) * 64 * HDIM + (kt) * 64, (buf) + (c) * 4096 + wbase)
#define STAGE_B(buf, c, kt) glds16(gB + (size_t)(c) * 64 * HDIM + (kt) * 64, (buf) + 16384 + (c) * 4096 + wbase)

    STAGE_B(buf0, 0, 0); STAGE_B(buf0, 1, 0);
    STAGE_A(buf0, 0, 0); STAGE_A(buf0, 1, 0); STAGE_A(buf0, 2, 0); STAGE_A(buf0, 3, 0);
    STAGE_B(buf1, 0, 1); STAGE_B(buf1, 1, 1);
    STAGE_A(buf1, 0, 1); STAGE_A(buf1, 2, 1);
    asm volatile("s_waitcnt vmcnt(4)" ::: "memory");
    __builtin_amdgcn_s_barrier();

    f32x4 acc[8][2] = {};
    u16* pc = buf0;
    u16* pn = buf1;

#pragma unroll 1
    for (int tt = 0; tt < 32; ++tt) {
        bf16x8 bfr[2][2], afr[4][2];
#pragma unroll
        for (int nf = 0; nf < 2; ++nf)
#pragma unroll
            for (int kk = 0; kk < 2; ++kk)
                bfr[nf][kk] = *(const bf16x8*)(pc + offB[nf][kk]);
#pragma unroll
        for (int mf = 0; mf < 4; ++mf)
#pragma unroll
            for (int kk = 0; kk < 2; ++kk)
                afr[mf][kk] = *(const bf16x8*)(pc + offA[mf][kk]);
        if (tt + 1 < 32) { STAGE_A(pn, 1, tt + 1); STAGE_A(pn, 3, tt + 1); }
        __builtin_amdgcn_s_barrier();
        asm volatile("s_waitcnt lgkmcnt(0)");
        __builtin_amdgcn_sched_barrier(0);
        __builtin_amdgcn_s_setprio(1);
#pragma unroll
        for (int mf = 0; mf < 4; ++mf)
#pragma unroll
            for (int nf = 0; nf < 2; ++nf)
#pragma unroll
                for (int kk = 0; kk < 2; ++kk)
                    acc[mf][nf] = __builtin_amdgcn_mfma_f32_16x16x32_bf16(
                        afr[mf][kk], bfr[nf][kk], acc[mf][nf], 0, 0, 0);
        __builtin_amdgcn_s_setprio(0);
        __builtin_amdgcn_s_barrier();

#pragma unroll
        for (int mf = 0; mf < 4; ++mf)
#pragma unroll
            for (int kk = 0; kk < 2; ++kk)
                afr[mf][kk] = *(const bf16x8*)(pc + offA[4 + mf][kk]);
        if (tt + 2 < 32) {
            STAGE_B(pc, 0, tt + 2); STAGE_B(pc, 1, tt + 2);
            STAGE_A(pc, 0, tt + 2); STAGE_A(pc, 2, tt + 2);
        }
        __builtin_amdgcn_s_barrier();
        asm volatile("s_waitcnt lgkmcnt(0)");
        __builtin_amdgcn_sched_barrier(0);
        __builtin_amdgcn_s_setprio(1);
#pragma unroll
        for (int mf = 0; mf < 4; ++mf)
#pragma unroll
            for (int nf = 0; nf < 2; ++nf)
#pragma unroll
                for (int kk = 0; kk < 2; ++kk)
                    acc[4 + mf][nf] = __builtin_amdgcn_mfma_f32_16x16x32_bf16(
                        afr[mf][kk], bfr[nf][kk], acc[4 + mf][nf], 0, 0, 0);
        __builtin_amdgcn_s_setprio(0);
        if (tt + 2 < 32)      { asm volatile("s_waitcnt vmcnt(4)" ::: "memory"); }
        else if (tt + 1 < 32) { asm volatile("s_waitcnt vmcnt(0)" ::: "memory"); }
        __builtin_amdgcn_s_barrier();
        u16* tmp = pc; pc = pn; pn = tmp;
    }
#undef STAGE_A
#undef STAGE_B

#pragma unroll
    for (int nf = 0; nf < 2; ++nf) {
        const int n = n0 + wn * 32 + nf * 16 + l15;
        const float bv = bias[n];
#pragma unroll
        for (int mf = 0; mf < 8; ++mf) {
            const int mb = m0 + wr * 128 + mf * 16 + (l4 << 2);
#pragma unroll
            for (int r = 0; r < 4; ++r) {
                const float v = acc[mf][nf][r] + bv;
                if (mode == 0)
                    ((u16*)outp)[(size_t)(mb + r) * HDIM + n] = f2bf(silu_f(v));
                else
                    ((float*)outp)[(size_t)(mb + r) * HDIM + n] = v;
            }
        }
    }
}

// ---------------------------------------------------------------------------
// Fused SiLU-attention + gating.  128 q-rows/block, LDS-staged K (single buf)
// + V (double buf) via glds with XOR swizzle (pre-swizzled source, rule #21).
// Per k-tile: stage V(kt+1) | QK^T | lgkm+barrier | stage K(kt+1) | PV |
// vmcnt(0)+barrier.  LDS 70 KB -> 2 blocks/CU.  XCD keying bh%8.
// Layout (u16 idx): K [8192] @0, V dbuf [2][8192] @8192, Ps [128][72] @24576,
// relh f32[1024] @33792.  Total 71680 B.
__global__ __launch_bounds__(256) void attn_fused(
    const u16* __restrict__ Qb, const u16* __restrict__ Kb,
    const u16* __restrict__ VTg, const u16* __restrict__ Ub,
    const float* __restrict__ rel, u16* __restrict__ G)
{
    extern __shared__ u16 alds[];
    u16* Ps = alds + 24576;
    float* relh = (float*)(alds + 33792);

    // Decode: XCD = idx%8 = bh%8 (L2 locality); complementary qt2 pairing.
    const int idx = blockIdx.x;
    const int half = idx >> 8, r5 = idx & 255;
    const int bh8 = r5 & 7;
    const int q8 = (r5 >> 3) & 7;
    const int bhhi = (r5 >> 6) & 3;
    const int bh = (half * 4 + bhhi) * 8 + bh8;
    const int qt2 = half ? 7 - q8 : q8;
    const int b = bh >> 4, h = bh & 15;
    const int qb0 = qt2 * 128;
    const int t = threadIdx.x, lane = t & 63, w = t >> 6;
    const int l15 = lane & 15, l4 = lane >> 4;
    const size_t rowbase = (size_t)b * SEQLEN;
    const int col0 = h * HEADD;
    const float scale = 0.088388347648318447f;   // 1/sqrt(128)

    for (int i = t; i < 1024; i += 256) relh[i] = rel[(size_t)(1023 + i) * NHEADS + h];

    // Staging source addresses (pre-swizzled so linear glds lands XOR-swizzled)
    const int rK = t >> 4;                       // K row-in-chunk 0..15
    const int cK = (t & 15) ^ (rK & 7);          // swizzled 16B-chunk (of 16)
    const u16* gK = Kb + (rowbase + rK) * HDIM + col0 + cK * 8;
    const int rV = t >> 3;                       // VT row-in-chunk 0..31
    const int cV = (t & 7) ^ (rV & 7);           // swizzled 16B-chunk (of 8)
    const u16* gV = VTg + ((size_t)bh * HEADD + rV) * SEQLEN + cV * 8;
    const int sdst = w * 512;                    // per-wave LDS slice (u16)

    // Q A-frags in registers: 2 q-frags x 4 k-chunks
    bf16x8 aq[2][4];
#pragma unroll
    for (int qf = 0; qf < 2; ++qf) {
        const int qrow = qb0 + w * 32 + qf * 16 + l15;
#pragma unroll
        for (int dc = 0; dc < 4; ++dc)
            aq[qf][dc] = *(const bf16x8*)&Qb[(rowbase + qrow) * HDIM + col0 + dc * 32 + (l4 << 3)];
    }

    f32x4 oacc[2][8] = {};
    const int nkt = 2 * qt2 + 2;

#define STAGE_K(kt) do {                                                        \
    const size_t ko_ = (size_t)(kt) * 64;                                       \
    _Pragma("unroll") for (int c = 0; c < 4; ++c)                               \
        glds16(gK + (ko_ + c * 16) * HDIM, alds + c * 2048 + sdst);             \
} while (0)
#define STAGE_V(kt, bsel) do {                                                  \
    u16* vb_ = alds + 8192 + ((bsel) ? 8192 : 0);                               \
    const size_t ko_ = (size_t)(kt) * 64;                                       \
    _Pragma("unroll") for (int c = 0; c < 4; ++c)                               \
        glds16(gV + (size_t)c * 32 * SEQLEN + ko_, vb_ + c * 2048 + sdst);      \
} while (0)

    STAGE_K(0); STAGE_V(0, 0);
    asm volatile("s_waitcnt vmcnt(0)" ::: "memory");
    __builtin_amdgcn_s_barrier();

    int cur = 0;
#pragma unroll 1
    for (int kt = 0; kt < nkt; ++kt) {
        const int k0 = kt * 64;
        if (kt + 1 < nkt) STAGE_V(kt + 1, cur ^ 1);
        const u16* kb = alds;
        const u16* vb = alds + 8192 + (cur ? 8192 : 0);

        // QK^T + rel + causal mask + silu -> Ps
#pragma unroll
        for (int kf = 0; kf < 4; ++kf) {
            const int krow = kf * 16 + l15;
            f32x4 s0 = {}, s1 = {};
            __builtin_amdgcn_s_setprio(1);
#pragma unroll
            for (int dc = 0; dc < 4; ++dc) {
                bf16x8 bk = *(const bf16x8*)&kb[krow * 128 + (((dc * 4 + l4) ^ (krow & 7)) << 3)];
                s0 = __builtin_amdgcn_mfma_f32_16x16x32_bf16(aq[0][dc], bk, s0, 0, 0, 0);
                s1 = __builtin_amdgcn_mfma_f32_16x16x32_bf16(aq[1][dc], bk, s1, 0, 0, 0);
            }
            __builtin_amdgcn_s_setprio(0);
            const int kabs = k0 + krow;
#pragma unroll
            for (int qf = 0; qf < 2; ++qf) {
                const f32x4 s = qf ? s1 : s0;
#pragma unroll
                for (int r = 0; r < 4; ++r) {
                    const int qabs = qb0 + w * 32 + qf * 16 + (l4 << 2) + r;
                    float v = 0.f;
                    if (kabs <= qabs) {
                        const float sc = s[r] * scale + relh[qabs - kabs];
                        v = silu_f(sc);
                    }
                    Ps[(w * 32 + qf * 16 + (l4 << 2) + r) * 72 + kf * 16 + l15] = f2bf(v);
                }
            }
        }
        asm volatile("s_waitcnt lgkmcnt(0)" ::: "memory");
        __builtin_amdgcn_s_barrier();                 // Kbuf free (all QK^T reads done)
        if (kt + 1 < nkt) STAGE_K(kt + 1);

        // PV: O[32q][128d] += P[32q][64k] @ V[64k][128d]; Ps rows wave-private.
        bf16x8 ap[2][2];
#pragma unroll
        for (int qf = 0; qf < 2; ++qf)
#pragma unroll
            for (int kc = 0; kc < 2; ++kc)
                ap[qf][kc] = *(const bf16x8*)&Ps[(w * 32 + qf * 16 + l15) * 72 + kc * 32 + (l4 << 3)];
        __builtin_amdgcn_s_setprio(1);
#pragma unroll
        for (int df = 0; df < 8; ++df) {
            const int vrow = df * 16 + l15;
#pragma unroll
            for (int kc = 0; kc < 2; ++kc) {
                bf16x8 bv = *(const bf16x8*)&vb[vrow * 64 + (((kc * 4 + l4) ^ (vrow & 7)) << 3)];
                oacc[0][df] = __builtin_amdgcn_mfma_f32_16x16x32_bf16(ap[0][kc], bv, oacc[0][df], 0, 0, 0);
                oacc[1][df] = __builtin_amdgcn_mfma_f32_16x16x32_bf16(ap[1][kc], bv, oacc[1][df], 0, 0, 0);
            }
        }
        __builtin_amdgcn_s_setprio(0);
        asm volatile("s_waitcnt vmcnt(0) lgkmcnt(0)" ::: "memory");  // next K,V landed
        __builtin_amdgcn_s_barrier();
        cur ^= 1;
    }
#undef STAGE_K
#undef STAGE_V

    // G = O * U
#pragma unroll
    for (int qf = 0; qf < 2; ++qf)
#pragma unroll
        for (int df = 0; df < 8; ++df) {
            const int d = df * 16 + l15;
#pragma unroll
            for (int r = 0; r < 4; ++r) {
                const int qabs = qb0 + w * 32 + qf * 16 + (l4 << 2) + r;
                const size_t ga = (rowbase + qabs) * HDIM + col0 + d;
                G[ga] = f2bf(oacc[qf][df][r] * bf2f(Ub[ga]));
            }
        }
}

// ---------------------------------------------------------------------------
extern "C" void kernel_launch(void* const* d_in, const int* in_sizes, int n_in,
                              void* d_out, int out_size, void* d_ws, size_t ws_size,
                              hipStream_t stream) {
    const float* query = (const float*)d_in[0];
    const float* key_  = (const float*)d_in[1];
    const float* value = (const float*)d_in[2];
    // d_in[3] attn_mask: causal by construction, handled analytically.
    const float* Wq  = (const float*)d_in[4];  const float* bq  = (const float*)d_in[5];
    const float* Wk  = (const float*)d_in[6];  const float* bk  = (const float*)d_in[7];
    const float* Wv  = (const float*)d_in[8];  const float* bv  = (const float*)d_in[9];
    const float* Wu  = (const float*)d_in[10]; const float* bu  = (const float*)d_in[11];
    const float* Wf2 = (const float*)d_in[12]; const float* bf2 = (const float*)d_in[13];
    const float* rel = (const float*)d_in[14];

    // Workspace (88 MiB): WT 8 | Xbf 16 | Q(=G) 16 | K 16 | V 16 | U 16
    char* ws = (char*)d_ws;
    const size_t WBYTES = (size_t)HDIM * HDIM * 2;   // 8 MiB
    const size_t ABYTES = (size_t)4096 * HDIM * 2;   // 16 MiB
    u16* WT   = (u16*)ws;
    u16* Xbf  = (u16*)(ws + WBYTES);
    u16* Qbuf = (u16*)(ws + WBYTES + 1 * ABYTES);
    u16* Kbuf = (u16*)(ws + WBYTES + 2 * ABYTES);
    u16* Vbuf = (u16*)(ws + WBYTES + 3 * ABYTES);
    u16* Ubuf = (u16*)(ws + WBYTES + 4 * ABYTES);
    u16* Gbuf = Qbuf;          // attn reads its own Q rows, then writes them as G
    u16* VTg  = Xbf;           // free after V GEMM; reused for transposed V

    dim3 tpb(256);
    dim3 tgrid(32, 32);        // W transpose tiles
    dim3 vgrid(32, 64);        // V transpose
    const int n8 = 4096 * HDIM / 8;
    const size_t GLDS = 98304; // 96 KiB dynamic LDS for gemm256
    const size_t ALDS = 71680; // 70 KiB dynamic LDS for attn_fused (2 blocks/CU)

    f32_to_bf16<<<2048, tpb, 0, stream>>>(query, Xbf, n8);
    transpose_w<<<tgrid, tpb, 0, stream>>>(Wq, WT);
    gemm256<<<256, 512, GLDS, stream>>>(Xbf, WT, bq, Qbuf, 0);
    transpose_w<<<tgrid, tpb, 0, stream>>>(Wu, WT);
    gemm256<<<256, 512, GLDS, stream>>>(Xbf, WT, bu, Ubuf, 0);
    f32_to_bf16<<<2048, tpb, 0, stream>>>(key_, Xbf, n8);
    transpose_w<<<tgrid, tpb, 0, stream>>>(Wk, WT);
    gemm256<<<256, 512, GLDS, stream>>>(Xbf, WT, bk, Kbuf, 0);
    f32_to_bf16<<<2048, tpb, 0, stream>>>(value, Xbf, n8);
    transpose_w<<<tgrid, tpb, 0, stream>>>(Wv, WT);
    gemm256<<<256, 512, GLDS, stream>>>(Xbf, WT, bv, Vbuf, 0);
    transpose_v<<<vgrid, tpb, 0, stream>>>(Vbuf, VTg);
    attn_fused<<<512, tpb, ALDS, stream>>>(Qbuf, Kbuf, VTg, Ubuf, rel, Gbuf);
    transpose_w<<<tgrid, tpb, 0, stream>>>(Wf2, WT);
    gemm256<<<256, 512, GLDS, stream>>>(Gbuf, WT, bf2, d_out, 1);
}

// Round 13
// 389.092 us; speedup vs baseline: 1.3865x; 1.0176x over previous
//
#include <hip/hip_runtime.h>
#include <stdint.h>

// Problem constants (B=4, S=1024, H=2048, NH=16, HD=128)
#define HDIM 2048
#define SEQLEN 1024
#define NHEADS 16
#define HEADD 128

typedef unsigned short u16;
typedef unsigned int u32;
typedef __attribute__((ext_vector_type(8))) short bf16x8;   // MFMA A/B frag
typedef __attribute__((ext_vector_type(8))) u16 u16x8;
typedef __attribute__((ext_vector_type(4))) u16 u16x4;
typedef __attribute__((ext_vector_type(4))) float f32x4;

__device__ __forceinline__ float bf2f(u16 u) {
    union { u32 i; float f; } v; v.i = ((u32)u) << 16; return v.f;
}
__device__ __forceinline__ u16 f2bf(float f) {
    union { float f; u32 i; } v; v.f = f;
    return (u16)((v.i + 0x7fffu + ((v.i >> 16) & 1u)) >> 16);  // RNE
}
__device__ __forceinline__ float silu_f(float x) {
    return x / (1.f + __expf(-x));
}
// Async global->LDS, 16B per lane. LDS dest = wave-uniform base + lane*16.
__device__ __forceinline__ void glds16(const void* g, void* l) {
    __builtin_amdgcn_global_load_lds(
        (const __attribute__((address_space(1))) u32*)g,
        (__attribute__((address_space(3))) u32*)l, 16, 0, 0);
}

// ---------------------------------------------------------------------------
// f32 -> bf16 bulk convert (8 elems/thread/iter), n8 = n/8.
__global__ __launch_bounds__(256) void f32_to_bf16(const float* __restrict__ in,
                                                   u16* __restrict__ out, int n8) {
    int i = blockIdx.x * 256 + threadIdx.x;
    const int stride = gridDim.x * 256;
    for (; i < n8; i += stride) {
        f32x4 a = *(const f32x4*)&in[(size_t)i * 8];
        f32x4 b = *(const f32x4*)&in[(size_t)i * 8 + 4];
        u16x8 o;
#pragma unroll
        for (int j = 0; j < 4; ++j) { o[j] = f2bf(a[j]); o[4 + j] = f2bf(b[j]); }
        *(u16x8*)&out[(size_t)i * 8] = o;
    }
}

// ---------------------------------------------------------------------------
// Transpose + downconvert W[k][n] (2048x2048 f32) -> WT[n][k] bf16.
__global__ __launch_bounds__(256) void transpose_w(const float* __restrict__ W,
                                                   u16* __restrict__ WT) {
    __shared__ u16 T[64][72];
    const int r0 = blockIdx.y * 64;   // k
    const int c0 = blockIdx.x * 64;   // n
    const int t = threadIdx.x;
#pragma unroll
    for (int c = t; c < 1024; c += 256) {
        const int r = c >> 4, cc = (c & 15) << 2;
        f32x4 v = *(const f32x4*)&W[(size_t)(r0 + r) * HDIM + c0 + cc];
        u16x4 o;
#pragma unroll
        for (int j = 0; j < 4; ++j) o[j] = f2bf(v[j]);
        *(u16x4*)&T[r][cc] = o;
    }
    __syncthreads();
#pragma unroll
    for (int c = t; c < 512; c += 256) {
        const int n = c & 63, kc = (c >> 6) << 3;
        u16x8 v;
#pragma unroll
        for (int j = 0; j < 8; ++j) v[j] = T[kc + j][n];
        *(u16x8*)&WT[(size_t)(c0 + n) * HDIM + r0 + kc] = v;
    }
}

// ---------------------------------------------------------------------------
// Transpose V: Vbuf[b*1024+s][h*128+d] bf16 -> VTg[(bh*128+d)*1024+s] bf16.
__global__ __launch_bounds__(256) void transpose_v(const u16* __restrict__ V,
                                                   u16* __restrict__ VT) {
    __shared__ u16 T[64][72];
    const int bh = blockIdx.y;
    const int st = (blockIdx.x & 15) * 64;
    const int dt = (blockIdx.x >> 4) * 64;
    const int b = bh >> 4, h = bh & 15;
    const int t = threadIdx.x;
#pragma unroll
    for (int c = t; c < 512; c += 256) {
        const int s = c >> 3, d8 = (c & 7) << 3;
        *(u16x8*)&T[s][d8] =
            *(const u16x8*)&V[(size_t)(b * SEQLEN + st + s) * HDIM + h * HEADD + dt + d8];
    }
    __syncthreads();
#pragma unroll
    for (int c = t; c < 512; c += 256) {
        const int d = c & 63, s8 = (c >> 6) << 3;
        u16x8 v;
#pragma unroll
        for (int j = 0; j < 8; ++j) v[j] = T[s8 + j][d];
        *(u16x8*)&VT[((size_t)bh * HEADD + dt + d) * SEQLEN + st + s8] = v;
    }
}

// ---------------------------------------------------------------------------
// Pipelined GEMM (unchanged): BM=256 x BN=128, BK=64, 8 waves.
__global__ __launch_bounds__(512) void gemm256(
    const u16* __restrict__ X, const u16* __restrict__ WT,
    const float* __restrict__ bias, void* __restrict__ outp, const int mode)
{
    extern __shared__ u16 lds[];   // 2 bufs x (A 16384 + B 8192) u16 = 96 KiB
    const int t = threadIdx.x;
    const int lane = t & 63, wid = t >> 6;
    const int l15 = lane & 15, l4 = lane >> 4;
    const int wr = wid >> 2, wn = wid & 3;

    const int bid = blockIdx.x;
    const int u = (bid & 7) * 32 + (bid >> 3);
    const int tm = u & 15, tn = u >> 4;
    const int m0 = tm * 256, n0 = tn * 128;

    const int ric = t >> 3;
    const int cse = (((t & 7) ^ (ric & 7)) << 3);
    const u16* gA = X  + (size_t)(m0 + ric) * HDIM + cse;
    const u16* gB = WT + (size_t)(n0 + ric) * HDIM + cse;

    u16* buf0 = lds;
    u16* buf1 = lds + 24576;
    const int wbase = wid * 512;

    int offA[8][2], offB[2][2];
#pragma unroll
    for (int mf = 0; mf < 8; ++mf) {
        const int row = wr * 128 + mf * 16 + l15;
#pragma unroll
        for (int kk = 0; kk < 2; ++kk)
            offA[mf][kk] = ((row * 128 + kk * 64 + l4 * 16) ^ ((row & 7) << 4)) >> 1;
    }
#pragma unroll
    for (int nf = 0; nf < 2; ++nf) {
        const int row = wn * 32 + nf * 16 + l15;
#pragma unroll
        for (int kk = 0; kk < 2; ++kk)
            offB[nf][kk] = 16384 + (((row * 128 + kk * 64 + l4 * 16) ^ ((row & 7) << 4)) >> 1);
    }

#define STAGE_A(buf, c, kt) glds16(gA + (size_t)(c) * 64 * HDIM + (kt) * 64, (buf) + (c) * 4096 + wbase)
#define STAGE_B(buf, c, kt) glds16(gB + (size_t)(c) * 64 * HDIM + (kt) * 64, (buf) + 16384 + (c) * 4096 + wbase)

    STAGE_B(buf0, 0, 0); STAGE_B(buf0, 1, 0);
    STAGE_A(buf0, 0, 0); STAGE_A(buf0, 1, 0); STAGE_A(buf0, 2, 0); STAGE_A(buf0, 3, 0);
    STAGE_B(buf1, 0, 1); STAGE_B(buf1, 1, 1);
    STAGE_A(buf1, 0, 1); STAGE_A(buf1, 2, 1);
    asm volatile("s_waitcnt vmcnt(4)" ::: "memory");
    __builtin_amdgcn_s_barrier();

    f32x4 acc[8][2] = {};
    u16* pc = buf0;
    u16* pn = buf1;

#pragma unroll 1
    for (int tt = 0; tt < 32; ++tt) {
        bf16x8 bfr[2][2], afr[4][2];
#pragma unroll
        for (int nf = 0; nf < 2; ++nf)
#pragma unroll
            for (int kk = 0; kk < 2; ++kk)
                bfr[nf][kk] = *(const bf16x8*)(pc + offB[nf][kk]);
#pragma unroll
        for (int mf = 0; mf < 4; ++mf)
#pragma unroll
            for (int kk = 0; kk < 2; ++kk)
                afr[mf][kk] = *(const bf16x8*)(pc + offA[mf][kk]);
        if (tt + 1 < 32) { STAGE_A(pn, 1, tt + 1); STAGE_A(pn, 3, tt + 1); }
        __builtin_amdgcn_s_barrier();
        asm volatile("s_waitcnt lgkmcnt(0)");
        __builtin_amdgcn_sched_barrier(0);
        __builtin_amdgcn_s_setprio(1);
#pragma unroll
        for (int mf = 0; mf < 4; ++mf)
#pragma unroll
            for (int nf = 0; nf < 2; ++nf)
#pragma unroll
                for (int kk = 0; kk < 2; ++kk)
                    acc[mf][nf] = __builtin_amdgcn_mfma_f32_16x16x32_bf16(
                        afr[mf][kk], bfr[nf][kk], acc[mf][nf], 0, 0, 0);
        __builtin_amdgcn_s_setprio(0);
        __builtin_amdgcn_s_barrier();

#pragma unroll
        for (int mf = 0; mf < 4; ++mf)
#pragma unroll
            for (int kk = 0; kk < 2; ++kk)
                afr[mf][kk] = *(const bf16x8*)(pc + offA[4 + mf][kk]);
        if (tt + 2 < 32) {
            STAGE_B(pc, 0, tt + 2); STAGE_B(pc, 1, tt + 2);
            STAGE_A(pc, 0, tt + 2); STAGE_A(pc, 2, tt + 2);
        }
        __builtin_amdgcn_s_barrier();
        asm volatile("s_waitcnt lgkmcnt(0)");
        __builtin_amdgcn_sched_barrier(0);
        __builtin_amdgcn_s_setprio(1);
#pragma unroll
        for (int mf = 0; mf < 4; ++mf)
#pragma unroll
            for (int nf = 0; nf < 2; ++nf)
#pragma unroll
                for (int kk = 0; kk < 2; ++kk)
                    acc[4 + mf][nf] = __builtin_amdgcn_mfma_f32_16x16x32_bf16(
                        afr[mf][kk], bfr[nf][kk], acc[4 + mf][nf], 0, 0, 0);
        __builtin_amdgcn_s_setprio(0);
        if (tt + 2 < 32)      { asm volatile("s_waitcnt vmcnt(4)" ::: "memory"); }
        else if (tt + 1 < 32) { asm volatile("s_waitcnt vmcnt(0)" ::: "memory"); }
        __builtin_amdgcn_s_barrier();
        u16* tmp = pc; pc = pn; pn = tmp;
    }
#undef STAGE_A
#undef STAGE_B

#pragma unroll
    for (int nf = 0; nf < 2; ++nf) {
        const int n = n0 + wn * 32 + nf * 16 + l15;
        const float bv = bias[n];
#pragma unroll
        for (int mf = 0; mf < 8; ++mf) {
            const int mb = m0 + wr * 128 + mf * 16 + (l4 << 2);
#pragma unroll
            for (int r = 0; r < 4; ++r) {
                const float v = acc[mf][nf][r] + bv;
                if (mode == 0)
                    ((u16*)outp)[(size_t)(mb + r) * HDIM + n] = f2bf(silu_f(v));
                else
                    ((float*)outp)[(size_t)(mb + r) * HDIM + n] = v;
            }
        }
    }
}

// ---------------------------------------------------------------------------
// Fused SiLU-attention + gating, balanced-pair blocks: block handles q-subtile
// j (short, active kt<=j) AND q-subtile 15-j (long, all kt), same (b,h) —
// per-block work = 17 MFMA-tile units for every j -> uniform block duration,
// sustained 2 blocks/CU.  K single-buf + V double-buf LDS staging with XOR
// swizzle (pre-swizzled source), stage-early pipeline (round-12-verified).
// LDS (u16 idx): K [8192] @0, V dbuf [2][8192] @8192, Ps [128][72] @24576
// (rows 0-63 long, 64-127 short), relh f32[1024] @33792.  Total 71680 B.
__global__ __launch_bounds__(256) void attn_fused(
    const u16* __restrict__ Qb, const u16* __restrict__ Kb,
    const u16* __restrict__ VTg, const u16* __restrict__ Ub,
    const float* __restrict__ rel, u16* __restrict__ G)
{
    extern __shared__ u16 alds[];
    u16* Ps = alds + 24576;
    float* relh = (float*)(alds + 33792);

    // Decode: XCD = idx%8 = bh%8 (L2 locality); j = paired subtile index.
    const int idx = blockIdx.x;
    const int bh8 = idx & 7;
    const int j = (idx >> 3) & 7;
    const int bhhi = idx >> 6;            // 0..7
    const int bh = bhhi * 8 + bh8;
    const int b = bh >> 4, h = bh & 15;
    const int qS0 = j * 64;               // short subtile
    const int qL0 = (15 - j) * 64;        // long subtile
    const int nkt = 16 - j;
    const int t = threadIdx.x, lane = t & 63, w = t >> 6;
    const int l15 = lane & 15, l4 = lane >> 4;
    const size_t rowbase = (size_t)b * SEQLEN;
    const int col0 = h * HEADD;
    const float scale = 0.088388347648318447f;   // 1/sqrt(128)

    for (int i = t; i < 1024; i += 256) relh[i] = rel[(size_t)(1023 + i) * NHEADS + h];

    // Staging source addresses (pre-swizzled so linear glds lands XOR-swizzled)
    const int rK = t >> 4;                       // K row-in-chunk 0..15
    const int cK = (t & 15) ^ (rK & 7);          // swizzled 16B-chunk (of 16)
    const u16* gK = Kb + (rowbase + rK) * HDIM + col0 + cK * 8;
    const int rV = t >> 3;                       // VT row-in-chunk 0..31
    const int cV = (t & 7) ^ (rV & 7);           // swizzled 16B-chunk (of 8)
    const u16* gV = VTg + ((size_t)bh * HEADD + rV) * SEQLEN + cV * 8;
    const int sdst = w * 512;                    // per-wave LDS slice (u16)

    // Q A-frags in registers: long + short subtile, wave's 16 rows each
    bf16x8 aqL[4], aqS[4];
    {
        const int qrowL = qL0 + w * 16 + l15;
        const int qrowS = qS0 + w * 16 + l15;
#pragma unroll
        for (int dc = 0; dc < 4; ++dc) {
            aqL[dc] = *(const bf16x8*)&Qb[(rowbase + qrowL) * HDIM + col0 + dc * 32 + (l4 << 3)];
            aqS[dc] = *(const bf16x8*)&Qb[(rowbase + qrowS) * HDIM + col0 + dc * 32 + (l4 << 3)];
        }
    }

    f32x4 oaccL[8] = {}, oaccS[8] = {};

#define STAGE_K(kt) do {                                                        \
    const size_t ko_ = (size_t)(kt) * 64;                                       \
    _Pragma("unroll") for (int c = 0; c < 4; ++c)                               \
        glds16(gK + (ko_ + c * 16) * HDIM, alds + c * 2048 + sdst);             \
} while (0)
#define STAGE_V(kt, bsel) do {                                                  \
    u16* vb_ = alds + 8192 + ((bsel) ? 8192 : 0);                               \
    const size_t ko_ = (size_t)(kt) * 64;                                       \
    _Pragma("unroll") for (int c = 0; c < 4; ++c)                               \
        glds16(gV + (size_t)c * 32 * SEQLEN + ko_, vb_ + c * 2048 + sdst);      \
} while (0)

    STAGE_K(0); STAGE_V(0, 0);
    asm volatile("s_waitcnt vmcnt(0)" ::: "memory");
    __builtin_amdgcn_s_barrier();

    int cur = 0;
#pragma unroll 1
    for (int kt = 0; kt < nkt; ++kt) {
        const int k0 = kt * 64;
        const bool doS = (kt <= j);               // block-uniform
        if (kt + 1 < nkt) STAGE_V(kt + 1, cur ^ 1);
        const u16* kb = alds;
        const u16* vb = alds + 8192 + (cur ? 8192 : 0);

        // QK^T + rel + causal mask + silu -> Ps (long always, short if active)
#pragma unroll
        for (int kf = 0; kf < 4; ++kf) {
            const int krow = kf * 16 + l15;
            f32x4 sL = {}, sS = {};
            __builtin_amdgcn_s_setprio(1);
#pragma unroll
            for (int dc = 0; dc < 4; ++dc) {
                bf16x8 bk = *(const bf16x8*)&kb[krow * 128 + (((dc * 4 + l4) ^ (krow & 7)) << 3)];
                sL = __builtin_amdgcn_mfma_f32_16x16x32_bf16(aqL[dc], bk, sL, 0, 0, 0);
                if (doS) sS = __builtin_amdgcn_mfma_f32_16x16x32_bf16(aqS[dc], bk, sS, 0, 0, 0);
            }
            __builtin_amdgcn_s_setprio(0);
            const int kabs = k0 + krow;
            const int prow = w * 16 + (l4 << 2);
#pragma unroll
            for (int r = 0; r < 4; ++r) {
                const int qabsL = qL0 + prow + r;
                float vL = 0.f;
                if (kabs <= qabsL) vL = silu_f(sL[r] * scale + relh[qabsL - kabs]);
                Ps[(prow + r) * 72 + kf * 16 + l15] = f2bf(vL);
            }
            if (doS) {
#pragma unroll
                for (int r = 0; r < 4; ++r) {
                    const int qabsS = qS0 + prow + r;
                    float vS = 0.f;
                    if (kabs <= qabsS) vS = silu_f(sS[r] * scale + relh[qabsS - kabs]);
                    Ps[(64 + prow + r) * 72 + kf * 16 + l15] = f2bf(vS);
                }
            }
        }
        asm volatile("s_waitcnt lgkmcnt(0)" ::: "memory");
        __builtin_amdgcn_s_barrier();                 // Kbuf free
        if (kt + 1 < nkt) STAGE_K(kt + 1);

        // PV (Ps rows wave-private; V^T swizzled reads)
        bf16x8 apL[2], apS[2];
#pragma unroll
        for (int kc = 0; kc < 2; ++kc) {
            apL[kc] = *(const bf16x8*)&Ps[(w * 16 + l15) * 72 + kc * 32 + (l4 << 3)];
            if (doS) apS[kc] = *(const bf16x8*)&Ps[(64 + w * 16 + l15) * 72 + kc * 32 + (l4 << 3)];
        }
        __builtin_amdgcn_s_setprio(1);
#pragma unroll
        for (int df = 0; df < 8; ++df) {
            const int vrow = df * 16 + l15;
#pragma unroll
            for (int kc = 0; kc < 2; ++kc) {
                bf16x8 bv = *(const bf16x8*)&vb[vrow * 64 + (((kc * 4 + l4) ^ (vrow & 7)) << 3)];
                oaccL[df] = __builtin_amdgcn_mfma_f32_16x16x32_bf16(apL[kc], bv, oaccL[df], 0, 0, 0);
                if (doS) oaccS[df] = __builtin_amdgcn_mfma_f32_16x16x32_bf16(apS[kc], bv, oaccS[df], 0, 0, 0);
            }
        }
        __builtin_amdgcn_s_setprio(0);
        asm volatile("s_waitcnt vmcnt(0) lgkmcnt(0)" ::: "memory");  // next K,V landed
        __builtin_amdgcn_s_barrier();
        cur ^= 1;
    }
#undef STAGE_K
#undef STAGE_V

    // G = O * U for both subtiles
#pragma unroll
    for (int df = 0; df < 8; ++df) {
        const int d = df * 16 + l15;
#pragma unroll
        for (int r = 0; r < 4; ++r) {
            const int qr = w * 16 + (l4 << 2) + r;
            const size_t gaL = (rowbase + qL0 + qr) * HDIM + col0 + d;
            G[gaL] = f2bf(oaccL[df][r] * bf2f(Ub[gaL]));
            const size_t gaS = (rowbase + qS0 + qr) * HDIM + col0 + d;
            G[gaS] = f2bf(oaccS[df][r] * bf2f(Ub[gaS]));
        }
    }
}

// ---------------------------------------------------------------------------
extern "C" void kernel_launch(void* const* d_in, const int* in_sizes, int n_in,
                              void* d_out, int out_size, void* d_ws, size_t ws_size,
                              hipStream_t stream) {
    const float* query = (const float*)d_in[0];
    const float* key_  = (const float*)d_in[1];
    const float* value = (const float*)d_in[2];
    // d_in[3] attn_mask: causal by construction, handled analytically.
    const float* Wq  = (const float*)d_in[4];  const float* bq  = (const float*)d_in[5];
    const float* Wk  = (const float*)d_in[6];  const float* bk  = (const float*)d_in[7];
    const float* Wv  = (const float*)d_in[8];  const float* bv  = (const float*)d_in[9];
    const float* Wu  = (const float*)d_in[10]; const float* bu  = (const float*)d_in[11];
    const float* Wf2 = (const float*)d_in[12]; const float* bf2 = (const float*)d_in[13];
    const float* rel = (const float*)d_in[14];

    // Workspace (88 MiB): WT 8 | Xbf 16 | Q(=G) 16 | K 16 | V 16 | U 16
    char* ws = (char*)d_ws;
    const size_t WBYTES = (size_t)HDIM * HDIM * 2;   // 8 MiB
    const size_t ABYTES = (size_t)4096 * HDIM * 2;   // 16 MiB
    u16* WT   = (u16*)ws;
    u16* Xbf  = (u16*)(ws + WBYTES);
    u16* Qbuf = (u16*)(ws + WBYTES + 1 * ABYTES);
    u16* Kbuf = (u16*)(ws + WBYTES + 2 * ABYTES);
    u16* Vbuf = (u16*)(ws + WBYTES + 3 * ABYTES);
    u16* Ubuf = (u16*)(ws + WBYTES + 4 * ABYTES);
    u16* Gbuf = Qbuf;          // attn reads its own Q rows, then writes them as G
    u16* VTg  = Xbf;           // free after V GEMM; reused for transposed V

    dim3 tpb(256);
    dim3 tgrid(32, 32);        // W transpose tiles
    dim3 vgrid(32, 64);        // V transpose
    const int n8 = 4096 * HDIM / 8;
    const size_t GLDS = 98304; // 96 KiB dynamic LDS for gemm256
    const size_t ALDS = 71680; // 70 KiB dynamic LDS for attn_fused (2 blocks/CU)

    f32_to_bf16<<<2048, tpb, 0, stream>>>(query, Xbf, n8);
    transpose_w<<<tgrid, tpb, 0, stream>>>(Wq, WT);
    gemm256<<<256, 512, GLDS, stream>>>(Xbf, WT, bq, Qbuf, 0);
    transpose_w<<<tgrid, tpb, 0, stream>>>(Wu, WT);
    gemm256<<<256, 512, GLDS, stream>>>(Xbf, WT, bu, Ubuf, 0);
    f32_to_bf16<<<2048, tpb, 0, stream>>>(key_, Xbf, n8);
    transpose_w<<<tgrid, tpb, 0, stream>>>(Wk, WT);
    gemm256<<<256, 512, GLDS, stream>>>(Xbf, WT, bk, Kbuf, 0);
    f32_to_bf16<<<2048, tpb, 0, stream>>>(value, Xbf, n8);
    transpose_w<<<tgrid, tpb, 0, stream>>>(Wv, WT);
    gemm256<<<256, 512, GLDS, stream>>>(Xbf, WT, bv, Vbuf, 0);
    transpose_v<<<vgrid, tpb, 0, stream>>>(Vbuf, VTg);
    attn_fused<<<512, tpb, ALDS, stream>>>(Qbuf, Kbuf, VTg, Ubuf, rel, Gbuf);
    transpose_w<<<tgrid, tpb, 0, stream>>>(Wf2, WT);
    gemm256<<<256, 512, GLDS, stream>>>(Gbuf, WT, bf2, d_out, 1);
}

// Round 14
// 375.528 us; speedup vs baseline: 1.4366x; 1.0361x over previous
//
#include <hip/hip_runtime.h>
#include <stdint.h>

// Problem constants (B=4, S=1024, H=2048, NH=16, HD=128)
#define HDIM 2048
#define SEQLEN 1024
#define NHEADS 16
#define HEADD 128

typedef unsigned short u16;
typedef unsigned int u32;
typedef __attribute__((ext_vector_type(8))) short bf16x8;   // MFMA A/B frag
typedef __attribute__((ext_vector_type(8))) u16 u16x8;
typedef __attribute__((ext_vector_type(4))) u16 u16x4;
typedef __attribute__((ext_vector_type(4))) float f32x4;

__device__ __forceinline__ float bf2f(u16 u) {
    union { u32 i; float f; } v; v.i = ((u32)u) << 16; return v.f;
}
__device__ __forceinline__ u16 f2bf(float f) {
    union { float f; u32 i; } v; v.f = f;
    return (u16)((v.i + 0x7fffu + ((v.i >> 16) & 1u)) >> 16);  // RNE
}
// Fast silu: x * rcp(1+exp(-x)).  v_exp + v_rcp (~5 VALU) instead of the
// precise-divide sequence (~14 VALU).  1-ulp rcp is far below bf16 rounding.
__device__ __forceinline__ float silu_f(float x) {
    return x * __builtin_amdgcn_rcpf(1.f + __expf(-x));
}
// Async global->LDS, 16B per lane. LDS dest = wave-uniform base + lane*16.
__device__ __forceinline__ void glds16(const void* g, void* l) {
    __builtin_amdgcn_global_load_lds(
        (const __attribute__((address_space(1))) u32*)g,
        (__attribute__((address_space(3))) u32*)l, 16, 0, 0);
}

// ---------------------------------------------------------------------------
// f32 -> bf16 bulk convert (8 elems/thread/iter), n8 = n/8.
__global__ __launch_bounds__(256) void f32_to_bf16(const float* __restrict__ in,
                                                   u16* __restrict__ out, int n8) {
    int i = blockIdx.x * 256 + threadIdx.x;
    const int stride = gridDim.x * 256;
    for (; i < n8; i += stride) {
        f32x4 a = *(const f32x4*)&in[(size_t)i * 8];
        f32x4 b = *(const f32x4*)&in[(size_t)i * 8 + 4];
        u16x8 o;
#pragma unroll
        for (int j = 0; j < 4; ++j) { o[j] = f2bf(a[j]); o[4 + j] = f2bf(b[j]); }
        *(u16x8*)&out[(size_t)i * 8] = o;
    }
}

// ---------------------------------------------------------------------------
// Transpose + downconvert W[k][n] (2048x2048 f32) -> WT[n][k] bf16.
__global__ __launch_bounds__(256) void transpose_w(const float* __restrict__ W,
                                                   u16* __restrict__ WT) {
    __shared__ u16 T[64][72];
    const int r0 = blockIdx.y * 64;   // k
    const int c0 = blockIdx.x * 64;   // n
    const int t = threadIdx.x;
#pragma unroll
    for (int c = t; c < 1024; c += 256) {
        const int r = c >> 4, cc = (c & 15) << 2;
        f32x4 v = *(const f32x4*)&W[(size_t)(r0 + r) * HDIM + c0 + cc];
        u16x4 o;
#pragma unroll
        for (int j = 0; j < 4; ++j) o[j] = f2bf(v[j]);
        *(u16x4*)&T[r][cc] = o;
    }
    __syncthreads();
#pragma unroll
    for (int c = t; c < 512; c += 256) {
        const int n = c & 63, kc = (c >> 6) << 3;
        u16x8 v;
#pragma unroll
        for (int j = 0; j < 8; ++j) v[j] = T[kc + j][n];
        *(u16x8*)&WT[(size_t)(c0 + n) * HDIM + r0 + kc] = v;
    }
}

// ---------------------------------------------------------------------------
// Transpose V: Vbuf[b*1024+s][h*128+d] bf16 -> VTg[(bh*128+d)*1024+s] bf16.
__global__ __launch_bounds__(256) void transpose_v(const u16* __restrict__ V,
                                                   u16* __restrict__ VT) {
    __shared__ u16 T[64][72];
    const int bh = blockIdx.y;
    const int st = (blockIdx.x & 15) * 64;
    const int dt = (blockIdx.x >> 4) * 64;
    const int b = bh >> 4, h = bh & 15;
    const int t = threadIdx.x;
#pragma unroll
    for (int c = t; c < 512; c += 256) {
        const int s = c >> 3, d8 = (c & 7) << 3;
        *(u16x8*)&T[s][d8] =
            *(const u16x8*)&V[(size_t)(b * SEQLEN + st + s) * HDIM + h * HEADD + dt + d8];
    }
    __syncthreads();
#pragma unroll
    for (int c = t; c < 512; c += 256) {
        const int d = c & 63, s8 = (c >> 6) << 3;
        u16x8 v;
#pragma unroll
        for (int j = 0; j < 8; ++j) v[j] = T[s8 + j][d];
        *(u16x8*)&VT[((size_t)bh * HEADD + dt + d) * SEQLEN + st + s8] = v;
    }
}

// ---------------------------------------------------------------------------
// Pipelined GEMM (unchanged): BM=256 x BN=128, BK=64, 8 waves.
__global__ __launch_bounds__(512) void gemm256(
    const u16* __restrict__ X, const u16* __restrict__ WT,
    const float* __restrict__ bias, void* __restrict__ outp, const int mode)
{
    extern __shared__ u16 lds[];   // 2 bufs x (A 16384 + B 8192) u16 = 96 KiB
    const int t = threadIdx.x;
    const int lane = t & 63, wid = t >> 6;
    const int l15 = lane & 15, l4 = lane >> 4;
    const int wr = wid >> 2, wn = wid & 3;

    const int bid = blockIdx.x;
    const int u = (bid & 7) * 32 + (bid >> 3);
    const int tm = u & 15, tn = u >> 4;
    const int m0 = tm * 256, n0 = tn * 128;

    const int ric = t >> 3;
    const int cse = (((t & 7) ^ (ric & 7)) << 3);
    const u16* gA = X  + (size_t)(m0 + ric) * HDIM + cse;
    const u16* gB = WT + (size_t)(n0 + ric) * HDIM + cse;

    u16* buf0 = lds;
    u16* buf1 = lds + 24576;
    const int wbase = wid * 512;

    int offA[8][2], offB[2][2];
#pragma unroll
    for (int mf = 0; mf < 8; ++mf) {
        const int row = wr * 128 + mf * 16 + l15;
#pragma unroll
        for (int kk = 0; kk < 2; ++kk)
            offA[mf][kk] = ((row * 128 + kk * 64 + l4 * 16) ^ ((row & 7) << 4)) >> 1;
    }
#pragma unroll
    for (int nf = 0; nf < 2; ++nf) {
        const int row = wn * 32 + nf * 16 + l15;
#pragma unroll
        for (int kk = 0; kk < 2; ++kk)
            offB[nf][kk] = 16384 + (((row * 128 + kk * 64 + l4 * 16) ^ ((row & 7) << 4)) >> 1);
    }

#define STAGE_A(buf, c, kt) glds16(gA + (size_t)(c) * 64 * HDIM + (kt) * 64, (buf) + (c) * 4096 + wbase)
#define STAGE_B(buf, c, kt) glds16(gB + (size_t)(c) * 64 * HDIM + (kt) * 64, (buf) + 16384 + (c) * 4096 + wbase)

    STAGE_B(buf0, 0, 0); STAGE_B(buf0, 1, 0);
    STAGE_A(buf0, 0, 0); STAGE_A(buf0, 1, 0); STAGE_A(buf0, 2, 0); STAGE_A(buf0, 3, 0);
    STAGE_B(buf1, 0, 1); STAGE_B(buf1, 1, 1);
    STAGE_A(buf1, 0, 1); STAGE_A(buf1, 2, 1);
    asm volatile("s_waitcnt vmcnt(4)" ::: "memory");
    __builtin_amdgcn_s_barrier();

    f32x4 acc[8][2] = {};
    u16* pc = buf0;
    u16* pn = buf1;

#pragma unroll 1
    for (int tt = 0; tt < 32; ++tt) {
        bf16x8 bfr[2][2], afr[4][2];
#pragma unroll
        for (int nf = 0; nf < 2; ++nf)
#pragma unroll
            for (int kk = 0; kk < 2; ++kk)
                bfr[nf][kk] = *(const bf16x8*)(pc + offB[nf][kk]);
#pragma unroll
        for (int mf = 0; mf < 4; ++mf)
#pragma unroll
            for (int kk = 0; kk < 2; ++kk)
                afr[mf][kk] = *(const bf16x8*)(pc + offA[mf][kk]);
        if (tt + 1 < 32) { STAGE_A(pn, 1, tt + 1); STAGE_A(pn, 3, tt + 1); }
        __builtin_amdgcn_s_barrier();
        asm volatile("s_waitcnt lgkmcnt(0)");
        __builtin_amdgcn_sched_barrier(0);
        __builtin_amdgcn_s_setprio(1);
#pragma unroll
        for (int mf = 0; mf < 4; ++mf)
#pragma unroll
            for (int nf = 0; nf < 2; ++nf)
#pragma unroll
                for (int kk = 0; kk < 2; ++kk)
                    acc[mf][nf] = __builtin_amdgcn_mfma_f32_16x16x32_bf16(
                        afr[mf][kk], bfr[nf][kk], acc[mf][nf], 0, 0, 0);
        __builtin_amdgcn_s_setprio(0);
        __builtin_amdgcn_s_barrier();

#pragma unroll
        for (int mf = 0; mf < 4; ++mf)
#pragma unroll
            for (int kk = 0; kk < 2; ++kk)
                afr[mf][kk] = *(const bf16x8*)(pc + offA[4 + mf][kk]);
        if (tt + 2 < 32) {
            STAGE_B(pc, 0, tt + 2); STAGE_B(pc, 1, tt + 2);
            STAGE_A(pc, 0, tt + 2); STAGE_A(pc, 2, tt + 2);
        }
        __builtin_amdgcn_s_barrier();
        asm volatile("s_waitcnt lgkmcnt(0)");
        __builtin_amdgcn_sched_barrier(0);
        __builtin_amdgcn_s_setprio(1);
#pragma unroll
        for (int mf = 0; mf < 4; ++mf)
#pragma unroll
            for (int nf = 0; nf < 2; ++nf)
#pragma unroll
                for (int kk = 0; kk < 2; ++kk)
                    acc[4 + mf][nf] = __builtin_amdgcn_mfma_f32_16x16x32_bf16(
                        afr[mf][kk], bfr[nf][kk], acc[4 + mf][nf], 0, 0, 0);
        __builtin_amdgcn_s_setprio(0);
        if (tt + 2 < 32)      { asm volatile("s_waitcnt vmcnt(4)" ::: "memory"); }
        else if (tt + 1 < 32) { asm volatile("s_waitcnt vmcnt(0)" ::: "memory"); }
        __builtin_amdgcn_s_barrier();
        u16* tmp = pc; pc = pn; pn = tmp;
    }
#undef STAGE_A
#undef STAGE_B

#pragma unroll
    for (int nf = 0; nf < 2; ++nf) {
        const int n = n0 + wn * 32 + nf * 16 + l15;
        const float bv = bias[n];
#pragma unroll
        for (int mf = 0; mf < 8; ++mf) {
            const int mb = m0 + wr * 128 + mf * 16 + (l4 << 2);
#pragma unroll
            for (int r = 0; r < 4; ++r) {
                const float v = acc[mf][nf][r] + bv;
                if (mode == 0)
                    ((u16*)outp)[(size_t)(mb + r) * HDIM + n] = f2bf(silu_f(v));
                else
                    ((float*)outp)[(size_t)(mb + r) * HDIM + n] = v;
            }
        }
    }
}

// ---------------------------------------------------------------------------
// Fused SiLU-attention + gating, balanced-pair blocks (round-13 structure):
// block handles q-subtile j (short, kt<=j) + q-subtile 15-j (long, all kt) —
// uniform 17 tile-units per block.  K single-buf + V double-buf glds staging,
// XOR swizzle via pre-swizzled source, stage-early pipeline.
// LDS (u16 idx): K [8192] @0, V dbuf [2][8192] @8192, Ps [128][72] @24576,
// relh f32[1024] @33792.  Total 71680 B -> 2 blocks/CU.
__global__ __launch_bounds__(256) void attn_fused(
    const u16* __restrict__ Qb, const u16* __restrict__ Kb,
    const u16* __restrict__ VTg, const u16* __restrict__ Ub,
    const float* __restrict__ rel, u16* __restrict__ G)
{
    extern __shared__ u16 alds[];
    u16* Ps = alds + 24576;
    float* relh = (float*)(alds + 33792);

    const int idx = blockIdx.x;
    const int bh8 = idx & 7;
    const int j = (idx >> 3) & 7;
    const int bhhi = idx >> 6;            // 0..7
    const int bh = bhhi * 8 + bh8;
    const int b = bh >> 4, h = bh & 15;
    const int qS0 = j * 64;               // short subtile
    const int qL0 = (15 - j) * 64;        // long subtile
    const int nkt = 16 - j;
    const int t = threadIdx.x, lane = t & 63, w = t >> 6;
    const int l15 = lane & 15, l4 = lane >> 4;
    const size_t rowbase = (size_t)b * SEQLEN;
    const int col0 = h * HEADD;
    const float scale = 0.088388347648318447f;   // 1/sqrt(128)

    for (int i = t; i < 1024; i += 256) relh[i] = rel[(size_t)(1023 + i) * NHEADS + h];

    const int rK = t >> 4;
    const int cK = (t & 15) ^ (rK & 7);
    const u16* gK = Kb + (rowbase + rK) * HDIM + col0 + cK * 8;
    const int rV = t >> 3;
    const int cV = (t & 7) ^ (rV & 7);
    const u16* gV = VTg + ((size_t)bh * HEADD + rV) * SEQLEN + cV * 8;
    const int sdst = w * 512;

    bf16x8 aqL[4], aqS[4];
    {
        const int qrowL = qL0 + w * 16 + l15;
        const int qrowS = qS0 + w * 16 + l15;
#pragma unroll
        for (int dc = 0; dc < 4; ++dc) {
            aqL[dc] = *(const bf16x8*)&Qb[(rowbase + qrowL) * HDIM + col0 + dc * 32 + (l4 << 3)];
            aqS[dc] = *(const bf16x8*)&Qb[(rowbase + qrowS) * HDIM + col0 + dc * 32 + (l4 << 3)];
        }
    }

    f32x4 oaccL[8] = {}, oaccS[8] = {};

#define STAGE_K(kt) do {                                                        \
    const size_t ko_ = (size_t)(kt) * 64;                                       \
    _Pragma("unroll") for (int c = 0; c < 4; ++c)                               \
        glds16(gK + (ko_ + c * 16) * HDIM, alds + c * 2048 + sdst);             \
} while (0)
#define STAGE_V(kt, bsel) do {                                                  \
    u16* vb_ = alds + 8192 + ((bsel) ? 8192 : 0);                               \
    const size_t ko_ = (size_t)(kt) * 64;                                       \
    _Pragma("unroll") for (int c = 0; c < 4; ++c)                               \
        glds16(gV + (size_t)c * 32 * SEQLEN + ko_, vb_ + c * 2048 + sdst);      \
} while (0)

    STAGE_K(0); STAGE_V(0, 0);
    asm volatile("s_waitcnt vmcnt(0)" ::: "memory");
    __builtin_amdgcn_s_barrier();

    int cur = 0;
#pragma unroll 1
    for (int kt = 0; kt < nkt; ++kt) {
        const int k0 = kt * 64;
        const bool doS = (kt <= j);               // block-uniform
        if (kt + 1 < nkt) STAGE_V(kt + 1, cur ^ 1);
        const u16* kb = alds;
        const u16* vb = alds + 8192 + (cur ? 8192 : 0);

        // QK^T + rel + causal mask + silu -> Ps
#pragma unroll
        for (int kf = 0; kf < 4; ++kf) {
            const int krow = kf * 16 + l15;
            f32x4 sL = {}, sS = {};
            __builtin_amdgcn_s_setprio(1);
#pragma unroll
            for (int dc = 0; dc < 4; ++dc) {
                bf16x8 bk = *(const bf16x8*)&kb[krow * 128 + (((dc * 4 + l4) ^ (krow & 7)) << 3)];
                sL = __builtin_amdgcn_mfma_f32_16x16x32_bf16(aqL[dc], bk, sL, 0, 0, 0);
                if (doS) sS = __builtin_amdgcn_mfma_f32_16x16x32_bf16(aqS[dc], bk, sS, 0, 0, 0);
            }
            __builtin_amdgcn_s_setprio(0);
            const int kabs = k0 + krow;
            const int prow = w * 16 + (l4 << 2);
#pragma unroll
            for (int r = 0; r < 4; ++r) {
                const int qabsL = qL0 + prow + r;
                float vL = 0.f;
                if (kabs <= qabsL) vL = silu_f(fmaf(sL[r], scale, relh[qabsL - kabs]));
                Ps[(prow + r) * 72 + kf * 16 + l15] = f2bf(vL);
            }
            if (doS) {
#pragma unroll
                for (int r = 0; r < 4; ++r) {
                    const int qabsS = qS0 + prow + r;
                    float vS = 0.f;
                    if (kabs <= qabsS) vS = silu_f(fmaf(sS[r], scale, relh[qabsS - kabs]));
                    Ps[(64 + prow + r) * 72 + kf * 16 + l15] = f2bf(vS);
                }
            }
        }
        asm volatile("s_waitcnt lgkmcnt(0)" ::: "memory");
        __builtin_amdgcn_s_barrier();                 // Kbuf free
        if (kt + 1 < nkt) STAGE_K(kt + 1);

        // PV (Ps rows wave-private; V^T swizzled reads)
        bf16x8 apL[2], apS[2];
#pragma unroll
        for (int kc = 0; kc < 2; ++kc) {
            apL[kc] = *(const bf16x8*)&Ps[(w * 16 + l15) * 72 + kc * 32 + (l4 << 3)];
            if (doS) apS[kc] = *(const bf16x8*)&Ps[(64 + w * 16 + l15) * 72 + kc * 32 + (l4 << 3)];
        }
        __builtin_amdgcn_s_setprio(1);
#pragma unroll
        for (int df = 0; df < 8; ++df) {
            const int vrow = df * 16 + l15;
#pragma unroll
            for (int kc = 0; kc < 2; ++kc) {
                bf16x8 bv = *(const bf16x8*)&vb[vrow * 64 + (((kc * 4 + l4) ^ (vrow & 7)) << 3)];
                oaccL[df] = __builtin_amdgcn_mfma_f32_16x16x32_bf16(apL[kc], bv, oaccL[df], 0, 0, 0);
                if (doS) oaccS[df] = __builtin_amdgcn_mfma_f32_16x16x32_bf16(apS[kc], bv, oaccS[df], 0, 0, 0);
            }
        }
        __builtin_amdgcn_s_setprio(0);
        asm volatile("s_waitcnt vmcnt(0) lgkmcnt(0)" ::: "memory");  // next K,V landed
        __builtin_amdgcn_s_barrier();
        cur ^= 1;
    }
#undef STAGE_K
#undef STAGE_V

    // G = O * U for both subtiles
#pragma unroll
    for (int df = 0; df < 8; ++df) {
        const int d = df * 16 + l15;
#pragma unroll
        for (int r = 0; r < 4; ++r) {
            const int qr = w * 16 + (l4 << 2) + r;
            const size_t gaL = (rowbase + qL0 + qr) * HDIM + col0 + d;
            G[gaL] = f2bf(oaccL[df][r] * bf2f(Ub[gaL]));
            const size_t gaS = (rowbase + qS0 + qr) * HDIM + col0 + d;
            G[gaS] = f2bf(oaccS[df][r] * bf2f(Ub[gaS]));
        }
    }
}

// ---------------------------------------------------------------------------
extern "C" void kernel_launch(void* const* d_in, const int* in_sizes, int n_in,
                              void* d_out, int out_size, void* d_ws, size_t ws_size,
                              hipStream_t stream) {
    const float* query = (const float*)d_in[0];
    const float* key_  = (const float*)d_in[1];
    const float* value = (const float*)d_in[2];
    // d_in[3] attn_mask: causal by construction, handled analytically.
    const float* Wq  = (const float*)d_in[4];  const float* bq  = (const float*)d_in[5];
    const float* Wk  = (const float*)d_in[6];  const float* bk  = (const float*)d_in[7];
    const float* Wv  = (const float*)d_in[8];  const float* bv  = (const float*)d_in[9];
    const float* Wu  = (const float*)d_in[10]; const float* bu  = (const float*)d_in[11];
    const float* Wf2 = (const float*)d_in[12]; const float* bf2 = (const float*)d_in[13];
    const float* rel = (const float*)d_in[14];

    // Workspace (88 MiB): WT 8 | Xbf 16 | Q(=G) 16 | K 16 | V 16 | U 16
    char* ws = (char*)d_ws;
    const size_t WBYTES = (size_t)HDIM * HDIM * 2;   // 8 MiB
    const size_t ABYTES = (size_t)4096 * HDIM * 2;   // 16 MiB
    u16* WT   = (u16*)ws;
    u16* Xbf  = (u16*)(ws + WBYTES);
    u16* Qbuf = (u16*)(ws + WBYTES + 1 * ABYTES);
    u16* Kbuf = (u16*)(ws + WBYTES + 2 * ABYTES);
    u16* Vbuf = (u16*)(ws + WBYTES + 3 * ABYTES);
    u16* Ubuf = (u16*)(ws + WBYTES + 4 * ABYTES);
    u16* Gbuf = Qbuf;          // attn reads its own Q rows, then writes them as G
    u16* VTg  = Xbf;           // free after V GEMM; reused for transposed V

    dim3 tpb(256);
    dim3 tgrid(32, 32);        // W transpose tiles
    dim3 vgrid(32, 64);        // V transpose
    const int n8 = 4096 * HDIM / 8;
    const size_t GLDS = 98304; // 96 KiB dynamic LDS for gemm256
    const size_t ALDS = 71680; // 70 KiB dynamic LDS for attn_fused (2 blocks/CU)

    f32_to_bf16<<<2048, tpb, 0, stream>>>(query, Xbf, n8);
    transpose_w<<<tgrid, tpb, 0, stream>>>(Wq, WT);
    gemm256<<<256, 512, GLDS, stream>>>(Xbf, WT, bq, Qbuf, 0);
    transpose_w<<<tgrid, tpb, 0, stream>>>(Wu, WT);
    gemm256<<<256, 512, GLDS, stream>>>(Xbf, WT, bu, Ubuf, 0);
    f32_to_bf16<<<2048, tpb, 0, stream>>>(key_, Xbf, n8);
    transpose_w<<<tgrid, tpb, 0, stream>>>(Wk, WT);
    gemm256<<<256, 512, GLDS, stream>>>(Xbf, WT, bk, Kbuf, 0);
    f32_to_bf16<<<2048, tpb, 0, stream>>>(value, Xbf, n8);
    transpose_w<<<tgrid, tpb, 0, stream>>>(Wv, WT);
    gemm256<<<256, 512, GLDS, stream>>>(Xbf, WT, bv, Vbuf, 0);
    transpose_v<<<vgrid, tpb, 0, stream>>>(Vbuf, VTg);
    attn_fused<<<512, tpb, ALDS, stream>>>(Qbuf, Kbuf, VTg, Ubuf, rel, Gbuf);
    transpose_w<<<tgrid, tpb, 0, stream>>>(Wf2, WT);
    gemm256<<<256, 512, GLDS, stream>>>(Gbuf, WT, bf2, d_out, 1);
}

// Round 15
// 366.422 us; speedup vs baseline: 1.4723x; 1.0248x over previous
//
#include <hip/hip_runtime.h>
#include <stdint.h>

// Problem constants (B=4, S=1024, H=2048, NH=16, HD=128)
#define HDIM 2048
#define SEQLEN 1024
#define NHEADS 16
#define HEADD 128

typedef unsigned short u16;
typedef unsigned int u32;
typedef __attribute__((ext_vector_type(8))) short bf16x8;   // MFMA A/B frag
typedef __attribute__((ext_vector_type(8))) u16 u16x8;
typedef __attribute__((ext_vector_type(4))) u16 u16x4;
typedef __attribute__((ext_vector_type(4))) float f32x4;

__device__ __forceinline__ float bf2f(u16 u) {
    union { u32 i; float f; } v; v.i = ((u32)u) << 16; return v.f;
}
__device__ __forceinline__ u16 f2bf(float f) {
    union { float f; u32 i; } v; v.f = f;
    return (u16)((v.i + 0x7fffu + ((v.i >> 16) & 1u)) >> 16);  // RNE
}
__device__ __forceinline__ u16 f2bf_t(float f) {               // truncation (1 op)
    union { float f; u32 i; } v; v.f = f; return (u16)(v.i >> 16);
}
// Fast silu: x * rcp(1+exp(-x)).
__device__ __forceinline__ float silu_f(float x) {
    return x * __builtin_amdgcn_rcpf(1.f + __expf(-x));
}
// Async global->LDS, 16B per lane. LDS dest = wave-uniform base + lane*16.
__device__ __forceinline__ void glds16(const void* g, void* l) {
    __builtin_amdgcn_global_load_lds(
        (const __attribute__((address_space(1))) u32*)g,
        (__attribute__((address_space(3))) u32*)l, 16, 0, 0);
}

// ---------------------------------------------------------------------------
// f32 -> bf16 bulk convert (8 elems/thread/iter), n8 = n/8.
__global__ __launch_bounds__(256) void f32_to_bf16(const float* __restrict__ in,
                                                   u16* __restrict__ out, int n8) {
    int i = blockIdx.x * 256 + threadIdx.x;
    const int stride = gridDim.x * 256;
    for (; i < n8; i += stride) {
        f32x4 a = *(const f32x4*)&in[(size_t)i * 8];
        f32x4 b = *(const f32x4*)&in[(size_t)i * 8 + 4];
        u16x8 o;
#pragma unroll
        for (int j = 0; j < 4; ++j) { o[j] = f2bf(a[j]); o[4 + j] = f2bf(b[j]); }
        *(u16x8*)&out[(size_t)i * 8] = o;
    }
}

// ---------------------------------------------------------------------------
// Transpose + downconvert W[k][n] (2048x2048 f32) -> WT[n][k] bf16.
__global__ __launch_bounds__(256) void transpose_w(const float* __restrict__ W,
                                                   u16* __restrict__ WT) {
    __shared__ u16 T[64][72];
    const int r0 = blockIdx.y * 64;   // k
    const int c0 = blockIdx.x * 64;   // n
    const int t = threadIdx.x;
#pragma unroll
    for (int c = t; c < 1024; c += 256) {
        const int r = c >> 4, cc = (c & 15) << 2;
        f32x4 v = *(const f32x4*)&W[(size_t)(r0 + r) * HDIM + c0 + cc];
        u16x4 o;
#pragma unroll
        for (int j = 0; j < 4; ++j) o[j] = f2bf(v[j]);
        *(u16x4*)&T[r][cc] = o;
    }
    __syncthreads();
#pragma unroll
    for (int c = t; c < 512; c += 256) {
        const int n = c & 63, kc = (c >> 6) << 3;
        u16x8 v;
#pragma unroll
        for (int j = 0; j < 8; ++j) v[j] = T[kc + j][n];
        *(u16x8*)&WT[(size_t)(c0 + n) * HDIM + r0 + kc] = v;
    }
}

// ---------------------------------------------------------------------------
// Transpose V: Vbuf[b*1024+s][h*128+d] bf16 -> VTg[(bh*128+d)*1024+s] bf16.
__global__ __launch_bounds__(256) void transpose_v(const u16* __restrict__ V,
                                                   u16* __restrict__ VT) {
    __shared__ u16 T[64][72];
    const int bh = blockIdx.y;
    const int st = (blockIdx.x & 15) * 64;
    const int dt = (blockIdx.x >> 4) * 64;
    const int b = bh >> 4, h = bh & 15;
    const int t = threadIdx.x;
#pragma unroll
    for (int c = t; c < 512; c += 256) {
        const int s = c >> 3, d8 = (c & 7) << 3;
        *(u16x8*)&T[s][d8] =
            *(const u16x8*)&V[(size_t)(b * SEQLEN + st + s) * HDIM + h * HEADD + dt + d8];
    }
    __syncthreads();
#pragma unroll
    for (int c = t; c < 512; c += 256) {
        const int d = c & 63, s8 = (c >> 6) << 3;
        u16x8 v;
#pragma unroll
        for (int j = 0; j < 8; ++j) v[j] = T[s8 + j][d];
        *(u16x8*)&VT[((size_t)bh * HEADD + dt + d) * SEQLEN + st + s8] = v;
    }
}

// ---------------------------------------------------------------------------
// Pipelined GEMM, 128x128 tile for 2 blocks/CU: BK=64, 4 waves (2Mx2N),
// per-wave 64x64 output.  Double-buffered LDS 64 KiB, XOR swizzle via
// pre-swizzled source, counted vmcnt(6), 2 phases x 16 MFMA with setprio.
// Grid 512 (32 M x 16 N) = 2 resident blocks/CU -> cross-block drain cover.
// Phase discipline: phase0 reads B(all)+A chunks{0,2}, prefetches pn A1,A3;
// phase1 reads A chunks{1,3} (B in regs), prefetches pc B0-3,A0,A2 (tt+2).
// mode 0: silu -> bf16 out; mode 1: bias only -> f32 out.
__global__ __launch_bounds__(256) void gemm128(
    const u16* __restrict__ X, const u16* __restrict__ WT,
    const float* __restrict__ bias, void* __restrict__ outp, const int mode)
{
    extern __shared__ u16 lds[];   // 2 bufs x (A 8192 + B 8192) u16 = 64 KiB
    const int t = threadIdx.x;
    const int lane = t & 63, wid = t >> 6;       // 4 waves
    const int l15 = lane & 15, l4 = lane >> 4;
    const int wr = wid >> 1, wn = wid & 1;

    const int bid = blockIdx.x;                  // 512 blocks
    const int u = (bid & 7) * 64 + (bid >> 3);   // XCD-bijective
    const int tm = u & 31, tn = u >> 5;          // 32 M-tiles x 16 N-tiles
    const int m0 = tm * 128, n0 = tn * 128;

    const int ric = t >> 3;                      // row in 32-row chunk
    const int cse = (((t & 7) ^ (ric & 7)) << 3);
    const u16* gA = X  + (size_t)(m0 + ric) * HDIM + cse;
    const u16* gB = WT + (size_t)(n0 + ric) * HDIM + cse;

    u16* buf0 = lds;                             // A @0, B @8192 (u16)
    u16* buf1 = lds + 16384;
    const int wbase = wid * 512;                 // 4 waves x 1KB per 4KB chunk

    int offA[4][2], offB[4][2];
#pragma unroll
    for (int i = 0; i < 4; ++i) {
        const int row = wr * 64 + i * 16 + l15;
#pragma unroll
        for (int kk = 0; kk < 2; ++kk)
            offA[i][kk] = ((row * 128 + kk * 64 + l4 * 16) ^ ((row & 7) << 4)) >> 1;
    }
#pragma unroll
    for (int j = 0; j < 4; ++j) {
        const int row = wn * 64 + j * 16 + l15;
#pragma unroll
        for (int kk = 0; kk < 2; ++kk)
            offB[j][kk] = 8192 + ((((row * 128 + kk * 64 + l4 * 16) ^ ((row & 7) << 4))) >> 1);
    }

#define STAGE_A(buf, c, kt) glds16(gA + (size_t)(c) * 32 * HDIM + (kt) * 64, (buf) + (c) * 2048 + wbase)
#define STAGE_B(buf, c, kt) glds16(gB + (size_t)(c) * 32 * HDIM + (kt) * 64, (buf) + 8192 + (c) * 2048 + wbase)

    // Prologue: tile0 full (8 loads) + tile1 head B0-3,A0,A2 (6 loads).
    STAGE_B(buf0, 0, 0); STAGE_B(buf0, 1, 0); STAGE_B(buf0, 2, 0); STAGE_B(buf0, 3, 0);
    STAGE_A(buf0, 0, 0); STAGE_A(buf0, 1, 0); STAGE_A(buf0, 2, 0); STAGE_A(buf0, 3, 0);
    STAGE_B(buf1, 0, 1); STAGE_B(buf1, 1, 1); STAGE_B(buf1, 2, 1); STAGE_B(buf1, 3, 1);
    STAGE_A(buf1, 0, 1); STAGE_A(buf1, 2, 1);
    asm volatile("s_waitcnt vmcnt(6)" ::: "memory");   // tile0 landed
    __builtin_amdgcn_s_barrier();

    f32x4 acc[4][4] = {};
    u16* pc = buf0;
    u16* pn = buf1;

#pragma unroll 1
    for (int tt = 0; tt < 32; ++tt) {
        bf16x8 bfr[4][2], afr[2][2];
        // ---- phase 0: B all + A i=0,1 (chunks {0,2}); prefetch pn A1,A3 ----
#pragma unroll
        for (int j = 0; j < 4; ++j)
#pragma unroll
            for (int kk = 0; kk < 2; ++kk)
                bfr[j][kk] = *(const bf16x8*)(pc + offB[j][kk]);
#pragma unroll
        for (int i = 0; i < 2; ++i)
#pragma unroll
            for (int kk = 0; kk < 2; ++kk)
                afr[i][kk] = *(const bf16x8*)(pc + offA[i][kk]);
        if (tt + 1 < 32) { STAGE_A(pn, 1, tt + 1); STAGE_A(pn, 3, tt + 1); }
        __builtin_amdgcn_s_barrier();
        asm volatile("s_waitcnt lgkmcnt(0)");
        __builtin_amdgcn_sched_barrier(0);
        __builtin_amdgcn_s_setprio(1);
#pragma unroll
        for (int i = 0; i < 2; ++i)
#pragma unroll
            for (int j = 0; j < 4; ++j)
#pragma unroll
                for (int kk = 0; kk < 2; ++kk)
                    acc[i][j] = __builtin_amdgcn_mfma_f32_16x16x32_bf16(
                        afr[i][kk], bfr[j][kk], acc[i][j], 0, 0, 0);
        __builtin_amdgcn_s_setprio(0);
        __builtin_amdgcn_s_barrier();

        // ---- phase 1: A i=2,3 (chunks {1,3}); prefetch pc tt+2 head ----
#pragma unroll
        for (int i = 0; i < 2; ++i)
#pragma unroll
            for (int kk = 0; kk < 2; ++kk)
                afr[i][kk] = *(const bf16x8*)(pc + offA[2 + i][kk]);
        if (tt + 2 < 32) {
            STAGE_B(pc, 0, tt + 2); STAGE_B(pc, 1, tt + 2);
            STAGE_B(pc, 2, tt + 2); STAGE_B(pc, 3, tt + 2);
            STAGE_A(pc, 0, tt + 2); STAGE_A(pc, 2, tt + 2);
        }
        __builtin_amdgcn_s_barrier();
        asm volatile("s_waitcnt lgkmcnt(0)");
        __builtin_amdgcn_sched_barrier(0);
        __builtin_amdgcn_s_setprio(1);
#pragma unroll
        for (int i = 0; i < 2; ++i)
#pragma unroll
            for (int j = 0; j < 4; ++j)
#pragma unroll
                for (int kk = 0; kk < 2; ++kk)
                    acc[2 + i][j] = __builtin_amdgcn_mfma_f32_16x16x32_bf16(
                        afr[i][kk], bfr[j][kk], acc[2 + i][j], 0, 0, 0);
        __builtin_amdgcn_s_setprio(0);
        if (tt + 2 < 32)      { asm volatile("s_waitcnt vmcnt(6)" ::: "memory"); }
        else if (tt + 1 < 32) { asm volatile("s_waitcnt vmcnt(0)" ::: "memory"); }
        __builtin_amdgcn_s_barrier();
        u16* tmp = pc; pc = pn; pn = tmp;
    }
#undef STAGE_A
#undef STAGE_B

    // Epilogue: C/D frag layout col = lane&15, row = (lane>>4)*4 + r
#pragma unroll
    for (int j = 0; j < 4; ++j) {
        const int n = n0 + wn * 64 + j * 16 + l15;
        const float bv = bias[n];
#pragma unroll
        for (int i = 0; i < 4; ++i) {
            const int mb = m0 + wr * 64 + i * 16 + (l4 << 2);
#pragma unroll
            for (int r = 0; r < 4; ++r) {
                const float v = acc[i][j][r] + bv;
                if (mode == 0)
                    ((u16*)outp)[(size_t)(mb + r) * HDIM + n] = f2bf(silu_f(v));
                else
                    ((float*)outp)[(size_t)(mb + r) * HDIM + n] = v;
            }
        }
    }
}

// ---------------------------------------------------------------------------
// Fused SiLU-attention + gating, balanced-pair blocks (round-13 structure).
// P-store uses truncation (f2bf_t) — feeds bf16 MFMA, bias << threshold.
// LDS (u16 idx): K [8192] @0, V dbuf [2][8192] @8192, Ps [128][72] @24576,
// relh f32[1024] @33792.  Total 71680 B -> 2 blocks/CU.
__global__ __launch_bounds__(256) void attn_fused(
    const u16* __restrict__ Qb, const u16* __restrict__ Kb,
    const u16* __restrict__ VTg, const u16* __restrict__ Ub,
    const float* __restrict__ rel, u16* __restrict__ G)
{
    extern __shared__ u16 alds[];
    u16* Ps = alds + 24576;
    float* relh = (float*)(alds + 33792);

    const int idx = blockIdx.x;
    const int bh8 = idx & 7;
    const int j = (idx >> 3) & 7;
    const int bhhi = idx >> 6;            // 0..7
    const int bh = bhhi * 8 + bh8;
    const int b = bh >> 4, h = bh & 15;
    const int qS0 = j * 64;               // short subtile
    const int qL0 = (15 - j) * 64;        // long subtile
    const int nkt = 16 - j;
    const int t = threadIdx.x, lane = t & 63, w = t >> 6;
    const int l15 = lane & 15, l4 = lane >> 4;
    const size_t rowbase = (size_t)b * SEQLEN;
    const int col0 = h * HEADD;
    const float scale = 0.088388347648318447f;   // 1/sqrt(128)

    for (int i = t; i < 1024; i += 256) relh[i] = rel[(size_t)(1023 + i) * NHEADS + h];

    const int rK = t >> 4;
    const int cK = (t & 15) ^ (rK & 7);
    const u16* gK = Kb + (rowbase + rK) * HDIM + col0 + cK * 8;
    const int rV = t >> 3;
    const int cV = (t & 7) ^ (rV & 7);
    const u16* gV = VTg + ((size_t)bh * HEADD + rV) * SEQLEN + cV * 8;
    const int sdst = w * 512;

    bf16x8 aqL[4], aqS[4];
    {
        const int qrowL = qL0 + w * 16 + l15;
        const int qrowS = qS0 + w * 16 + l15;
#pragma unroll
        for (int dc = 0; dc < 4; ++dc) {
            aqL[dc] = *(const bf16x8*)&Qb[(rowbase + qrowL) * HDIM + col0 + dc * 32 + (l4 << 3)];
            aqS[dc] = *(const bf16x8*)&Qb[(rowbase + qrowS) * HDIM + col0 + dc * 32 + (l4 << 3)];
        }
    }

    f32x4 oaccL[8] = {}, oaccS[8] = {};

#define STAGE_K(kt) do {                                                        \
    const size_t ko_ = (size_t)(kt) * 64;                                       \
    _Pragma("unroll") for (int c = 0; c < 4; ++c)                               \
        glds16(gK + (ko_ + c * 16) * HDIM, alds + c * 2048 + sdst);             \
} while (0)
#define STAGE_V(kt, bsel) do {                                                  \
    u16* vb_ = alds + 8192 + ((bsel) ? 8192 : 0);                               \
    const size_t ko_ = (size_t)(kt) * 64;                                       \
    _Pragma("unroll") for (int c = 0; c < 4; ++c)                               \
        glds16(gV + (size_t)c * 32 * SEQLEN + ko_, vb_ + c * 2048 + sdst);      \
} while (0)

    STAGE_K(0); STAGE_V(0, 0);
    asm volatile("s_waitcnt vmcnt(0)" ::: "memory");
    __builtin_amdgcn_s_barrier();

    int cur = 0;
#pragma unroll 1
    for (int kt = 0; kt < nkt; ++kt) {
        const int k0 = kt * 64;
        const bool doS = (kt <= j);               // block-uniform
        if (kt + 1 < nkt) STAGE_V(kt + 1, cur ^ 1);
        const u16* kb = alds;
        const u16* vb = alds + 8192 + (cur ? 8192 : 0);

        // QK^T + rel + causal mask + silu -> Ps
#pragma unroll
        for (int kf = 0; kf < 4; ++kf) {
            const int krow = kf * 16 + l15;
            f32x4 sL = {}, sS = {};
            __builtin_amdgcn_s_setprio(1);
#pragma unroll
            for (int dc = 0; dc < 4; ++dc) {
                bf16x8 bk = *(const bf16x8*)&kb[krow * 128 + (((dc * 4 + l4) ^ (krow & 7)) << 3)];
                sL = __builtin_amdgcn_mfma_f32_16x16x32_bf16(aqL[dc], bk, sL, 0, 0, 0);
                if (doS) sS = __builtin_amdgcn_mfma_f32_16x16x32_bf16(aqS[dc], bk, sS, 0, 0, 0);
            }
            __builtin_amdgcn_s_setprio(0);
            const int kabs = k0 + krow;
            const int prow = w * 16 + (l4 << 2);
#pragma unroll
            for (int r = 0; r < 4; ++r) {
                const int qabsL = qL0 + prow + r;
                float vL = 0.f;
                if (kabs <= qabsL) vL = silu_f(fmaf(sL[r], scale, relh[qabsL - kabs]));
                Ps[(prow + r) * 72 + kf * 16 + l15] = f2bf_t(vL);
            }
            if (doS) {
#pragma unroll
                for (int r = 0; r < 4; ++r) {
                    const int qabsS = qS0 + prow + r;
                    float vS = 0.f;
                    if (kabs <= qabsS) vS = silu_f(fmaf(sS[r], scale, relh[qabsS - kabs]));
                    Ps[(64 + prow + r) * 72 + kf * 16 + l15] = f2bf_t(vS);
                }
            }
        }
        asm volatile("s_waitcnt lgkmcnt(0)" ::: "memory");
        __builtin_amdgcn_s_barrier();                 // Kbuf free
        if (kt + 1 < nkt) STAGE_K(kt + 1);

        // PV (Ps rows wave-private; V^T swizzled reads)
        bf16x8 apL[2], apS[2];
#pragma unroll
        for (int kc = 0; kc < 2; ++kc) {
            apL[kc] = *(const bf16x8*)&Ps[(w * 16 + l15) * 72 + kc * 32 + (l4 << 3)];
            if (doS) apS[kc] = *(const bf16x8*)&Ps[(64 + w * 16 + l15) * 72 + kc * 32 + (l4 << 3)];
        }
        __builtin_amdgcn_s_setprio(1);
#pragma unroll
        for (int df = 0; df < 8; ++df) {
            const int vrow = df * 16 + l15;
#pragma unroll
            for (int kc = 0; kc < 2; ++kc) {
                bf16x8 bv = *(const bf16x8*)&vb[vrow * 64 + (((kc * 4 + l4) ^ (vrow & 7)) << 3)];
                oaccL[df] = __builtin_amdgcn_mfma_f32_16x16x32_bf16(apL[kc], bv, oaccL[df], 0, 0, 0);
                if (doS) oaccS[df] = __builtin_amdgcn_mfma_f32_16x16x32_bf16(apS[kc], bv, oaccS[df], 0, 0, 0);
            }
        }
        __builtin_amdgcn_s_setprio(0);
        asm volatile("s_waitcnt vmcnt(0) lgkmcnt(0)" ::: "memory");  // next K,V landed
        __builtin_amdgcn_s_barrier();
        cur ^= 1;
    }
#undef STAGE_K
#undef STAGE_V

    // G = O * U for both subtiles
#pragma unroll
    for (int df = 0; df < 8; ++df) {
        const int d = df * 16 + l15;
#pragma unroll
        for (int r = 0; r < 4; ++r) {
            const int qr = w * 16 + (l4 << 2) + r;
            const size_t gaL = (rowbase + qL0 + qr) * HDIM + col0 + d;
            G[gaL] = f2bf(oaccL[df][r] * bf2f(Ub[gaL]));
            const size_t gaS = (rowbase + qS0 + qr) * HDIM + col0 + d;
            G[gaS] = f2bf(oaccS[df][r] * bf2f(Ub[gaS]));
        }
    }
}

// ---------------------------------------------------------------------------
extern "C" void kernel_launch(void* const* d_in, const int* in_sizes, int n_in,
                              void* d_out, int out_size, void* d_ws, size_t ws_size,
                              hipStream_t stream) {
    const float* query = (const float*)d_in[0];
    const float* key_  = (const float*)d_in[1];
    const float* value = (const float*)d_in[2];
    // d_in[3] attn_mask: causal by construction, handled analytically.
    const float* Wq  = (const float*)d_in[4];  const float* bq  = (const float*)d_in[5];
    const float* Wk  = (const float*)d_in[6];  const float* bk  = (const float*)d_in[7];
    const float* Wv  = (const float*)d_in[8];  const float* bv  = (const float*)d_in[9];
    const float* Wu  = (const float*)d_in[10]; const float* bu  = (const float*)d_in[11];
    const float* Wf2 = (const float*)d_in[12]; const float* bf2 = (const float*)d_in[13];
    const float* rel = (const float*)d_in[14];

    // Workspace (88 MiB): WT 8 | Xbf 16 | Q(=G) 16 | K 16 | V 16 | U 16
    char* ws = (char*)d_ws;
    const size_t WBYTES = (size_t)HDIM * HDIM * 2;   // 8 MiB
    const size_t ABYTES = (size_t)4096 * HDIM * 2;   // 16 MiB
    u16* WT   = (u16*)ws;
    u16* Xbf  = (u16*)(ws + WBYTES);
    u16* Qbuf = (u16*)(ws + WBYTES + 1 * ABYTES);
    u16* Kbuf = (u16*)(ws + WBYTES + 2 * ABYTES);
    u16* Vbuf = (u16*)(ws + WBYTES + 3 * ABYTES);
    u16* Ubuf = (u16*)(ws + WBYTES + 4 * ABYTES);
    u16* Gbuf = Qbuf;          // attn reads its own Q rows, then writes them as G
    u16* VTg  = Xbf;           // free after V GEMM; reused for transposed V

    dim3 tpb(256);
    dim3 tgrid(32, 32);        // W transpose tiles
    dim3 vgrid(32, 64);        // V transpose
    const int n8 = 4096 * HDIM / 8;
    const size_t GLDS = 65536; // 64 KiB dynamic LDS for gemm128 (2 blocks/CU)
    const size_t ALDS = 71680; // 70 KiB dynamic LDS for attn_fused (2 blocks/CU)

    f32_to_bf16<<<2048, tpb, 0, stream>>>(query, Xbf, n8);
    transpose_w<<<tgrid, tpb, 0, stream>>>(Wq, WT);
    gemm128<<<512, tpb, GLDS, stream>>>(Xbf, WT, bq, Qbuf, 0);
    transpose_w<<<tgrid, tpb, 0, stream>>>(Wu, WT);
    gemm128<<<512, tpb, GLDS, stream>>>(Xbf, WT, bu, Ubuf, 0);
    f32_to_bf16<<<2048, tpb, 0, stream>>>(key_, Xbf, n8);
    transpose_w<<<tgrid, tpb, 0, stream>>>(Wk, WT);
    gemm128<<<512, tpb, GLDS, stream>>>(Xbf, WT, bk, Kbuf, 0);
    f32_to_bf16<<<2048, tpb, 0, stream>>>(value, Xbf, n8);
    transpose_w<<<tgrid, tpb, 0, stream>>>(Wv, WT);
    gemm128<<<512, tpb, GLDS, stream>>>(Xbf, WT, bv, Vbuf, 0);
    transpose_v<<<vgrid, tpb, 0, stream>>>(Vbuf, VTg);
    attn_fused<<<512, tpb, ALDS, stream>>>(Qbuf, Kbuf, VTg, Ubuf, rel, Gbuf);
    transpose_w<<<tgrid, tpb, 0, stream>>>(Wf2, WT);
    gemm128<<<512, tpb, GLDS, stream>>>(Gbuf, WT, bf2, d_out, 1);
}

// Round 16
// 359.921 us; speedup vs baseline: 1.4989x; 1.0181x over previous
//
#include <hip/hip_runtime.h>
#include <stdint.h>

// Problem constants (B=4, S=1024, H=2048, NH=16, HD=128)
#define HDIM 2048
#define SEQLEN 1024
#define NHEADS 16
#define HEADD 128

typedef unsigned short u16;
typedef unsigned int u32;
typedef __attribute__((ext_vector_type(8))) short bf16x8;   // MFMA A/B frag
typedef __attribute__((ext_vector_type(8))) u16 u16x8;
typedef __attribute__((ext_vector_type(4))) u16 u16x4;
typedef __attribute__((ext_vector_type(4))) float f32x4;

__device__ __forceinline__ float bf2f(u16 u) {
    union { u32 i; float f; } v; v.i = ((u32)u) << 16; return v.f;
}
__device__ __forceinline__ u16 f2bf(float f) {
    union { float f; u32 i; } v; v.f = f;
    return (u16)((v.i + 0x7fffu + ((v.i >> 16) & 1u)) >> 16);  // RNE
}
__device__ __forceinline__ u16 f2bf_t(float f) {               // truncation (1 op)
    union { float f; u32 i; } v; v.f = f; return (u16)(v.i >> 16);
}
// Fast silu: x * rcp(1+exp(-x)).
__device__ __forceinline__ float silu_f(float x) {
    return x * __builtin_amdgcn_rcpf(1.f + __expf(-x));
}
// Async global->LDS, 16B per lane. LDS dest = wave-uniform base + lane*16.
__device__ __forceinline__ void glds16(const void* g, void* l) {
    __builtin_amdgcn_global_load_lds(
        (const __attribute__((address_space(1))) u32*)g,
        (__attribute__((address_space(3))) u32*)l, 16, 0, 0);
}

// ---------------------------------------------------------------------------
// f32 -> bf16 bulk convert (8 elems/thread/iter), n8 = n/8.
__global__ __launch_bounds__(256) void f32_to_bf16(const float* __restrict__ in,
                                                   u16* __restrict__ out, int n8) {
    int i = blockIdx.x * 256 + threadIdx.x;
    const int stride = gridDim.x * 256;
    for (; i < n8; i += stride) {
        f32x4 a = *(const f32x4*)&in[(size_t)i * 8];
        f32x4 b = *(const f32x4*)&in[(size_t)i * 8 + 4];
        u16x8 o;
#pragma unroll
        for (int j = 0; j < 4; ++j) { o[j] = f2bf(a[j]); o[4 + j] = f2bf(b[j]); }
        *(u16x8*)&out[(size_t)i * 8] = o;
    }
}

// ---------------------------------------------------------------------------
// Transpose + downconvert W[k][n] (2048x2048 f32) -> WT[n][k] bf16.
__global__ __launch_bounds__(256) void transpose_w(const float* __restrict__ W,
                                                   u16* __restrict__ WT) {
    __shared__ u16 T[64][72];
    const int r0 = blockIdx.y * 64;   // k
    const int c0 = blockIdx.x * 64;   // n
    const int t = threadIdx.x;
#pragma unroll
    for (int c = t; c < 1024; c += 256) {
        const int r = c >> 4, cc = (c & 15) << 2;
        f32x4 v = *(const f32x4*)&W[(size_t)(r0 + r) * HDIM + c0 + cc];
        u16x4 o;
#pragma unroll
        for (int j = 0; j < 4; ++j) o[j] = f2bf(v[j]);
        *(u16x4*)&T[r][cc] = o;
    }
    __syncthreads();
#pragma unroll
    for (int c = t; c < 512; c += 256) {
        const int n = c & 63, kc = (c >> 6) << 3;
        u16x8 v;
#pragma unroll
        for (int j = 0; j < 8; ++j) v[j] = T[kc + j][n];
        *(u16x8*)&WT[(size_t)(c0 + n) * HDIM + r0 + kc] = v;
    }
}

// ---------------------------------------------------------------------------
// Transpose V: Vbuf[b*1024+s][h*128+d] bf16 -> VTg[(bh*128+d)*1024+s] bf16.
__global__ __launch_bounds__(256) void transpose_v(const u16* __restrict__ V,
                                                   u16* __restrict__ VT) {
    __shared__ u16 T[64][72];
    const int bh = blockIdx.y;
    const int st = (blockIdx.x & 15) * 64;
    const int dt = (blockIdx.x >> 4) * 64;
    const int b = bh >> 4, h = bh & 15;
    const int t = threadIdx.x;
#pragma unroll
    for (int c = t; c < 512; c += 256) {
        const int s = c >> 3, d8 = (c & 7) << 3;
        *(u16x8*)&T[s][d8] =
            *(const u16x8*)&V[(size_t)(b * SEQLEN + st + s) * HDIM + h * HEADD + dt + d8];
    }
    __syncthreads();
#pragma unroll
    for (int c = t; c < 512; c += 256) {
        const int d = c & 63, s8 = (c >> 6) << 3;
        u16x8 v;
#pragma unroll
        for (int j = 0; j < 8; ++j) v[j] = T[s8 + j][d];
        *(u16x8*)&VT[((size_t)bh * HEADD + dt + d) * SEQLEN + st + s8] = v;
    }
}

// ---------------------------------------------------------------------------
// 8-phase 256x256 GEMM (m201-style), QU-fused: C = silu(X @ W + bias) for
// Wq (n<2048) or Wu (n>=2048).  BK=64, 8 waves (2Mx4N), per-wave 128x64 out.
// 128 KB LDS dbuf.  Per K-tile 4 phases x 16 MFMA; prefetch units
// {A-P1,B-P1,B-P2,A-P3} (2 glds each) issued one-per-phase for tile t+1;
// counted waits vmcnt(4) at ends of P1,P2,P4 (ledger-verified), none at P3.
__global__ __launch_bounds__(512, 2) void gemm256_8p(
    const u16* __restrict__ X,
    const u16* __restrict__ WTq, const u16* __restrict__ WTu,
    const float* __restrict__ bq, const float* __restrict__ bu,
    u16* __restrict__ Qo, u16* __restrict__ Uo)
{
    extern __shared__ u16 lds[];   // 2 bufs x 32768 u16 (A @0, B @16384)
    const int t = threadIdx.x;
    const int lane = t & 63, wid = t >> 6;        // 8 waves
    const int l15 = lane & 15, l4 = lane >> 4;
    const int wr = wid >> 2, wn = wid & 3;        // 2M x 4N

    const int bid = blockIdx.x;                   // 256 blocks
    const int u = (bid & 7) * 32 + (bid >> 3);    // XCD-bijective
    const int tm = u & 15, tn = u >> 4;
    const int m0 = tm * 256;
    const int n0 = tn * 256;                      // 0..4095
    const u16* WT = (n0 < 2048) ? WTq : WTu;
    const float* bias = (n0 < 2048) ? bq : bu;
    u16* outp = (n0 < 2048) ? Qo : Uo;
    const int nc0 = n0 & 2047;

    // Staging sources (pre-swizzled col so linear glds lands XOR-swizzled)
    const int r64 = t >> 3;                       // 0..63
    const int cse = (((t & 7) ^ (r64 & 7)) << 3);
    const u16* gA = X + (size_t)(m0 + r64) * HDIM + cse;
    const int rB0 = (r64 >> 5) * 64 + (r64 & 31); // B sweep row mapping
    const u16* gB = WT + (size_t)(nc0 + rB0) * HDIM + cse;

    const int wbase = wid * 512;                              // A dst slice
    const int dstBw = (wid >> 2) * 4096 + (wid & 3) * 512;    // B dst slice

    // ds_read element offsets (u16, XOR-swizzled), within one buffer
    int offA[8][2], offB[4][2];
#pragma unroll
    for (int mf = 0; mf < 8; ++mf) {
        const int row = wr * 128 + mf * 16 + l15;
#pragma unroll
        for (int kk = 0; kk < 2; ++kk) {
            const int c = kk * 4 + l4;
            offA[mf][kk] = row * 64 + (((c) ^ (row & 7)) << 3);
        }
    }
#pragma unroll
    for (int nf = 0; nf < 4; ++nf) {
        const int row = wn * 64 + nf * 16 + l15;
#pragma unroll
        for (int kk = 0; kk < 2; ++kk) {
            const int c = kk * 4 + l4;
            offB[nf][kk] = 16384 + row * 64 + (((c) ^ (row & 7)) << 3);
        }
    }

#define SA(buf, rb, kt) glds16(gA + (size_t)(rb) * HDIM + (kt) * 64, \
                               lds + (buf) * 32768 + (rb) * 64 + wbase)
#define SB(buf, c, half, kt) glds16(gB + (size_t)((c) * 128 + (half) * 32) * HDIM + (kt) * 64, \
                               lds + (buf) * 32768 + 16384 + dstBw + (c) * 8192 + (half) * 2048)

    // Prologue: tile 0 units in order A-P1, B-P1, B-P2, A-P3 (8 glds)
    SA(0, 0, 0);    SA(0, 128, 0);
    SB(0, 0, 0, 0); SB(0, 1, 0, 0);
    SB(0, 0, 1, 0); SB(0, 1, 1, 0);
    SA(0, 64, 0);   SA(0, 192, 0);
    asm volatile("s_waitcnt vmcnt(4)" ::: "memory");   // A-P1,B-P1 landed
    __builtin_amdgcn_s_barrier();

    f32x4 acc[8][4] = {};
    int cur = 0;

#pragma unroll 1
    for (int kt = 0; kt < 32; ++kt) {
        const u16* pc = lds + cur * 32768;
        const int nb = cur ^ 1;
        const bool pf = (kt + 1 < 32);
        bf16x8 a[4][2], b0[2][2], b1[2][2];

        // ---- P1: read A mf0-3 + B nf0-1; issue A-P1(t+1) ----
#pragma unroll
        for (int mf = 0; mf < 4; ++mf)
#pragma unroll
            for (int kk = 0; kk < 2; ++kk)
                a[mf][kk] = *(const bf16x8*)(pc + offA[mf][kk]);
#pragma unroll
        for (int nf = 0; nf < 2; ++nf)
#pragma unroll
            for (int kk = 0; kk < 2; ++kk)
                b0[nf][kk] = *(const bf16x8*)(pc + offB[nf][kk]);
        if (pf) { SA(nb, 0, kt + 1); SA(nb, 128, kt + 1); }
        __builtin_amdgcn_s_barrier();
        asm volatile("s_waitcnt lgkmcnt(0)");
        __builtin_amdgcn_sched_barrier(0);
        __builtin_amdgcn_s_setprio(1);
#pragma unroll
        for (int mf = 0; mf < 4; ++mf)
#pragma unroll
            for (int nf = 0; nf < 2; ++nf)
#pragma unroll
                for (int kk = 0; kk < 2; ++kk)
                    acc[mf][nf] = __builtin_amdgcn_mfma_f32_16x16x32_bf16(
                        a[mf][kk], b0[nf][kk], acc[mf][nf], 0, 0, 0);
        __builtin_amdgcn_s_setprio(0);
        if (pf) { asm volatile("s_waitcnt vmcnt(4)" ::: "memory"); }
        else    { asm volatile("s_waitcnt vmcnt(2)" ::: "memory"); }
        __builtin_amdgcn_s_barrier();

        // ---- P2: read B nf2-3; issue B-P1(t+1) ----
#pragma unroll
        for (int nf = 0; nf < 2; ++nf)
#pragma unroll
            for (int kk = 0; kk < 2; ++kk)
                b1[nf][kk] = *(const bf16x8*)(pc + offB[2 + nf][kk]);
        if (pf) { SB(nb, 0, 0, kt + 1); SB(nb, 1, 0, kt + 1); }
        __builtin_amdgcn_s_barrier();
        asm volatile("s_waitcnt lgkmcnt(0)");
        __builtin_amdgcn_sched_barrier(0);
        __builtin_amdgcn_s_setprio(1);
#pragma unroll
        for (int mf = 0; mf < 4; ++mf)
#pragma unroll
            for (int nf = 0; nf < 2; ++nf)
#pragma unroll
                for (int kk = 0; kk < 2; ++kk)
                    acc[mf][2 + nf] = __builtin_amdgcn_mfma_f32_16x16x32_bf16(
                        a[mf][kk], b1[nf][kk], acc[mf][2 + nf], 0, 0, 0);
        __builtin_amdgcn_s_setprio(0);
        if (pf) { asm volatile("s_waitcnt vmcnt(4)" ::: "memory"); }
        else    { asm volatile("s_waitcnt vmcnt(0)" ::: "memory"); }
        __builtin_amdgcn_s_barrier();

        // ---- P3: read A mf4-7; issue B-P2(t+1) ----
#pragma unroll
        for (int mf = 0; mf < 4; ++mf)
#pragma unroll
            for (int kk = 0; kk < 2; ++kk)
                a[mf][kk] = *(const bf16x8*)(pc + offA[4 + mf][kk]);
        if (pf) { SB(nb, 0, 1, kt + 1); SB(nb, 1, 1, kt + 1); }
        __builtin_amdgcn_s_barrier();
        asm volatile("s_waitcnt lgkmcnt(0)");
        __builtin_amdgcn_sched_barrier(0);
        __builtin_amdgcn_s_setprio(1);
#pragma unroll
        for (int mf = 0; mf < 4; ++mf)
#pragma unroll
            for (int nf = 0; nf < 2; ++nf)
#pragma unroll
                for (int kk = 0; kk < 2; ++kk)
                    acc[4 + mf][nf] = __builtin_amdgcn_mfma_f32_16x16x32_bf16(
                        a[mf][kk], b0[nf][kk], acc[4 + mf][nf], 0, 0, 0);
        __builtin_amdgcn_s_setprio(0);
        __builtin_amdgcn_s_barrier();             // no vmcnt here (ledger)

        // ---- P4: no reads; issue A-P3(t+1) ----
        if (pf) { SA(nb, 64, kt + 1); SA(nb, 192, kt + 1); }
        __builtin_amdgcn_s_barrier();
        __builtin_amdgcn_s_setprio(1);
#pragma unroll
        for (int mf = 0; mf < 4; ++mf)
#pragma unroll
            for (int nf = 0; nf < 2; ++nf)
#pragma unroll
                for (int kk = 0; kk < 2; ++kk)
                    acc[4 + mf][2 + nf] = __builtin_amdgcn_mfma_f32_16x16x32_bf16(
                        a[mf][kk], b1[nf][kk], acc[4 + mf][2 + nf], 0, 0, 0);
        __builtin_amdgcn_s_setprio(0);
        if (pf) { asm volatile("s_waitcnt vmcnt(4)" ::: "memory"); }
        __builtin_amdgcn_s_barrier();
        cur ^= 1;
    }
#undef SA
#undef SB

    // Epilogue: silu + bf16 store.  C/D frag: col = lane&15, row = (lane>>4)*4+r
#pragma unroll
    for (int nf = 0; nf < 4; ++nf) {
        const int nc = nc0 + wn * 64 + nf * 16 + l15;
        const float bv = bias[nc];
#pragma unroll
        for (int mf = 0; mf < 8; ++mf) {
            const int mb = m0 + wr * 128 + mf * 16 + (l4 << 2);
#pragma unroll
            for (int r = 0; r < 4; ++r)
                outp[(size_t)(mb + r) * HDIM + nc] = f2bf(silu_f(acc[mf][nf][r] + bv));
        }
    }
}

// ---------------------------------------------------------------------------
// Pipelined GEMM 128x128 (unchanged from round 15): used for K, V, final.
__global__ __launch_bounds__(256) void gemm128(
    const u16* __restrict__ X, const u16* __restrict__ WT,
    const float* __restrict__ bias, void* __restrict__ outp, const int mode)
{
    extern __shared__ u16 lds[];   // 2 bufs x (A 8192 + B 8192) u16 = 64 KiB
    const int t = threadIdx.x;
    const int lane = t & 63, wid = t >> 6;       // 4 waves
    const int l15 = lane & 15, l4 = lane >> 4;
    const int wr = wid >> 1, wn = wid & 1;

    const int bid = blockIdx.x;                  // 512 blocks
    const int u = (bid & 7) * 64 + (bid >> 3);   // XCD-bijective
    const int tm = u & 31, tn = u >> 5;
    const int m0 = tm * 128, n0 = tn * 128;

    const int ric = t >> 3;
    const int cse = (((t & 7) ^ (ric & 7)) << 3);
    const u16* gA = X  + (size_t)(m0 + ric) * HDIM + cse;
    const u16* gB = WT + (size_t)(n0 + ric) * HDIM + cse;

    u16* buf0 = lds;
    u16* buf1 = lds + 16384;
    const int wbase = wid * 512;

    int offA[4][2], offB[4][2];
#pragma unroll
    for (int i = 0; i < 4; ++i) {
        const int row = wr * 64 + i * 16 + l15;
#pragma unroll
        for (int kk = 0; kk < 2; ++kk)
            offA[i][kk] = ((row * 128 + kk * 64 + l4 * 16) ^ ((row & 7) << 4)) >> 1;
    }
#pragma unroll
    for (int j = 0; j < 4; ++j) {
        const int row = wn * 64 + j * 16 + l15;
#pragma unroll
        for (int kk = 0; kk < 2; ++kk)
            offB[j][kk] = 8192 + ((((row * 128 + kk * 64 + l4 * 16) ^ ((row & 7) << 4))) >> 1);
    }

#define STAGE_A(buf, c, kt) glds16(gA + (size_t)(c) * 32 * HDIM + (kt) * 64, (buf) + (c) * 2048 + wbase)
#define STAGE_B(buf, c, kt) glds16(gB + (size_t)(c) * 32 * HDIM + (kt) * 64, (buf) + 8192 + (c) * 2048 + wbase)

    STAGE_B(buf0, 0, 0); STAGE_B(buf0, 1, 0); STAGE_B(buf0, 2, 0); STAGE_B(buf0, 3, 0);
    STAGE_A(buf0, 0, 0); STAGE_A(buf0, 1, 0); STAGE_A(buf0, 2, 0); STAGE_A(buf0, 3, 0);
    STAGE_B(buf1, 0, 1); STAGE_B(buf1, 1, 1); STAGE_B(buf1, 2, 1); STAGE_B(buf1, 3, 1);
    STAGE_A(buf1, 0, 1); STAGE_A(buf1, 2, 1);
    asm volatile("s_waitcnt vmcnt(6)" ::: "memory");
    __builtin_amdgcn_s_barrier();

    f32x4 acc[4][4] = {};
    u16* pc = buf0;
    u16* pn = buf1;

#pragma unroll 1
    for (int tt = 0; tt < 32; ++tt) {
        bf16x8 bfr[4][2], afr[2][2];
#pragma unroll
        for (int j = 0; j < 4; ++j)
#pragma unroll
            for (int kk = 0; kk < 2; ++kk)
                bfr[j][kk] = *(const bf16x8*)(pc + offB[j][kk]);
#pragma unroll
        for (int i = 0; i < 2; ++i)
#pragma unroll
            for (int kk = 0; kk < 2; ++kk)
                afr[i][kk] = *(const bf16x8*)(pc + offA[i][kk]);
        if (tt + 1 < 32) { STAGE_A(pn, 1, tt + 1); STAGE_A(pn, 3, tt + 1); }
        __builtin_amdgcn_s_barrier();
        asm volatile("s_waitcnt lgkmcnt(0)");
        __builtin_amdgcn_sched_barrier(0);
        __builtin_amdgcn_s_setprio(1);
#pragma unroll
        for (int i = 0; i < 2; ++i)
#pragma unroll
            for (int j = 0; j < 4; ++j)
#pragma unroll
                for (int kk = 0; kk < 2; ++kk)
                    acc[i][j] = __builtin_amdgcn_mfma_f32_16x16x32_bf16(
                        afr[i][kk], bfr[j][kk], acc[i][j], 0, 0, 0);
        __builtin_amdgcn_s_setprio(0);
        __builtin_amdgcn_s_barrier();

#pragma unroll
        for (int i = 0; i < 2; ++i)
#pragma unroll
            for (int kk = 0; kk < 2; ++kk)
                afr[i][kk] = *(const bf16x8*)(pc + offA[2 + i][kk]);
        if (tt + 2 < 32) {
            STAGE_B(pc, 0, tt + 2); STAGE_B(pc, 1, tt + 2);
            STAGE_B(pc, 2, tt + 2); STAGE_B(pc, 3, tt + 2);
            STAGE_A(pc, 0, tt + 2); STAGE_A(pc, 2, tt + 2);
        }
        __builtin_amdgcn_s_barrier();
        asm volatile("s_waitcnt lgkmcnt(0)");
        __builtin_amdgcn_sched_barrier(0);
        __builtin_amdgcn_s_setprio(1);
#pragma unroll
        for (int i = 0; i < 2; ++i)
#pragma unroll
            for (int j = 0; j < 4; ++j)
#pragma unroll
                for (int kk = 0; kk < 2; ++kk)
                    acc[2 + i][j] = __builtin_amdgcn_mfma_f32_16x16x32_bf16(
                        afr[i][kk], bfr[j][kk], acc[2 + i][j], 0, 0, 0);
        __builtin_amdgcn_s_setprio(0);
        if (tt + 2 < 32)      { asm volatile("s_waitcnt vmcnt(6)" ::: "memory"); }
        else if (tt + 1 < 32) { asm volatile("s_waitcnt vmcnt(0)" ::: "memory"); }
        __builtin_amdgcn_s_barrier();
        u16* tmp = pc; pc = pn; pn = tmp;
    }
#undef STAGE_A
#undef STAGE_B

#pragma unroll
    for (int j = 0; j < 4; ++j) {
        const int n = n0 + wn * 64 + j * 16 + l15;
        const float bv = bias[n];
#pragma unroll
        for (int i = 0; i < 4; ++i) {
            const int mb = m0 + wr * 64 + i * 16 + (l4 << 2);
#pragma unroll
            for (int r = 0; r < 4; ++r) {
                const float v = acc[i][j][r] + bv;
                if (mode == 0)
                    ((u16*)outp)[(size_t)(mb + r) * HDIM + n] = f2bf(silu_f(v));
                else
                    ((float*)outp)[(size_t)(mb + r) * HDIM + n] = v;
            }
        }
    }
}

// ---------------------------------------------------------------------------
// Fused SiLU-attention + gating (unchanged from round 15).
__global__ __launch_bounds__(256) void attn_fused(
    const u16* __restrict__ Qb, const u16* __restrict__ Kb,
    const u16* __restrict__ VTg, const u16* __restrict__ Ub,
    const float* __restrict__ rel, u16* __restrict__ G)
{
    extern __shared__ u16 alds[];
    u16* Ps = alds + 24576;
    float* relh = (float*)(alds + 33792);

    const int idx = blockIdx.x;
    const int bh8 = idx & 7;
    const int j = (idx >> 3) & 7;
    const int bhhi = idx >> 6;            // 0..7
    const int bh = bhhi * 8 + bh8;
    const int b = bh >> 4, h = bh & 15;
    const int qS0 = j * 64;               // short subtile
    const int qL0 = (15 - j) * 64;        // long subtile
    const int nkt = 16 - j;
    const int t = threadIdx.x, lane = t & 63, w = t >> 6;
    const int l15 = lane & 15, l4 = lane >> 4;
    const size_t rowbase = (size_t)b * SEQLEN;
    const int col0 = h * HEADD;
    const float scale = 0.088388347648318447f;   // 1/sqrt(128)

    for (int i = t; i < 1024; i += 256) relh[i] = rel[(size_t)(1023 + i) * NHEADS + h];

    const int rK = t >> 4;
    const int cK = (t & 15) ^ (rK & 7);
    const u16* gK = Kb + (rowbase + rK) * HDIM + col0 + cK * 8;
    const int rV = t >> 3;
    const int cV = (t & 7) ^ (rV & 7);
    const u16* gV = VTg + ((size_t)bh * HEADD + rV) * SEQLEN + cV * 8;
    const int sdst = w * 512;

    bf16x8 aqL[4], aqS[4];
    {
        const int qrowL = qL0 + w * 16 + l15;
        const int qrowS = qS0 + w * 16 + l15;
#pragma unroll
        for (int dc = 0; dc < 4; ++dc) {
            aqL[dc] = *(const bf16x8*)&Qb[(rowbase + qrowL) * HDIM + col0 + dc * 32 + (l4 << 3)];
            aqS[dc] = *(const bf16x8*)&Qb[(rowbase + qrowS) * HDIM + col0 + dc * 32 + (l4 << 3)];
        }
    }

    f32x4 oaccL[8] = {}, oaccS[8] = {};

#define STAGE_K(kt) do {                                                        \
    const size_t ko_ = (size_t)(kt) * 64;                                       \
    _Pragma("unroll") for (int c = 0; c < 4; ++c)                               \
        glds16(gK + (ko_ + c * 16) * HDIM, alds + c * 2048 + sdst);             \
} while (0)
#define STAGE_V(kt, bsel) do {                                                  \
    u16* vb_ = alds + 8192 + ((bsel) ? 8192 : 0);                               \
    const size_t ko_ = (size_t)(kt) * 64;                                       \
    _Pragma("unroll") for (int c = 0; c < 4; ++c)                               \
        glds16(gV + (size_t)c * 32 * SEQLEN + ko_, vb_ + c * 2048 + sdst);      \
} while (0)

    STAGE_K(0); STAGE_V(0, 0);
    asm volatile("s_waitcnt vmcnt(0)" ::: "memory");
    __builtin_amdgcn_s_barrier();

    int cur = 0;
#pragma unroll 1
    for (int kt = 0; kt < nkt; ++kt) {
        const int k0 = kt * 64;
        const bool doS = (kt <= j);               // block-uniform
        if (kt + 1 < nkt) STAGE_V(kt + 1, cur ^ 1);
        const u16* kb = alds;
        const u16* vb = alds + 8192 + (cur ? 8192 : 0);

#pragma unroll
        for (int kf = 0; kf < 4; ++kf) {
            const int krow = kf * 16 + l15;
            f32x4 sL = {}, sS = {};
            __builtin_amdgcn_s_setprio(1);
#pragma unroll
            for (int dc = 0; dc < 4; ++dc) {
                bf16x8 bk = *(const bf16x8*)&kb[krow * 128 + (((dc * 4 + l4) ^ (krow & 7)) << 3)];
                sL = __builtin_amdgcn_mfma_f32_16x16x32_bf16(aqL[dc], bk, sL, 0, 0, 0);
                if (doS) sS = __builtin_amdgcn_mfma_f32_16x16x32_bf16(aqS[dc], bk, sS, 0, 0, 0);
            }
            __builtin_amdgcn_s_setprio(0);
            const int kabs = k0 + krow;
            const int prow = w * 16 + (l4 << 2);
#pragma unroll
            for (int r = 0; r < 4; ++r) {
                const int qabsL = qL0 + prow + r;
                float vL = 0.f;
                if (kabs <= qabsL) vL = silu_f(fmaf(sL[r], scale, relh[qabsL - kabs]));
                Ps[(prow + r) * 72 + kf * 16 + l15] = f2bf_t(vL);
            }
            if (doS) {
#pragma unroll
                for (int r = 0; r < 4; ++r) {
                    const int qabsS = qS0 + prow + r;
                    float vS = 0.f;
                    if (kabs <= qabsS) vS = silu_f(fmaf(sS[r], scale, relh[qabsS - kabs]));
                    Ps[(64 + prow + r) * 72 + kf * 16 + l15] = f2bf_t(vS);
                }
            }
        }
        asm volatile("s_waitcnt lgkmcnt(0)" ::: "memory");
        __builtin_amdgcn_s_barrier();                 // Kbuf free
        if (kt + 1 < nkt) STAGE_K(kt + 1);

        bf16x8 apL[2], apS[2];
#pragma unroll
        for (int kc = 0; kc < 2; ++kc) {
            apL[kc] = *(const bf16x8*)&Ps[(w * 16 + l15) * 72 + kc * 32 + (l4 << 3)];
            if (doS) apS[kc] = *(const bf16x8*)&Ps[(64 + w * 16 + l15) * 72 + kc * 32 + (l4 << 3)];
        }
        __builtin_amdgcn_s_setprio(1);
#pragma unroll
        for (int df = 0; df < 8; ++df) {
            const int vrow = df * 16 + l15;
#pragma unroll
            for (int kc = 0; kc < 2; ++kc) {
                bf16x8 bv = *(const bf16x8*)&vb[vrow * 64 + (((kc * 4 + l4) ^ (vrow & 7)) << 3)];
                oaccL[df] = __builtin_amdgcn_mfma_f32_16x16x32_bf16(apL[kc], bv, oaccL[df], 0, 0, 0);
                if (doS) oaccS[df] = __builtin_amdgcn_mfma_f32_16x16x32_bf16(apS[kc], bv, oaccS[df], 0, 0, 0);
            }
        }
        __builtin_amdgcn_s_setprio(0);
        asm volatile("s_waitcnt vmcnt(0) lgkmcnt(0)" ::: "memory");
        __builtin_amdgcn_s_barrier();
        cur ^= 1;
    }
#undef STAGE_K
#undef STAGE_V

#pragma unroll
    for (int df = 0; df < 8; ++df) {
        const int d = df * 16 + l15;
#pragma unroll
        for (int r = 0; r < 4; ++r) {
            const int qr = w * 16 + (l4 << 2) + r;
            const size_t gaL = (rowbase + qL0 + qr) * HDIM + col0 + d;
            G[gaL] = f2bf(oaccL[df][r] * bf2f(Ub[gaL]));
            const size_t gaS = (rowbase + qS0 + qr) * HDIM + col0 + d;
            G[gaS] = f2bf(oaccS[df][r] * bf2f(Ub[gaS]));
        }
    }
}

// ---------------------------------------------------------------------------
extern "C" void kernel_launch(void* const* d_in, const int* in_sizes, int n_in,
                              void* d_out, int out_size, void* d_ws, size_t ws_size,
                              hipStream_t stream) {
    const float* query = (const float*)d_in[0];
    const float* key_  = (const float*)d_in[1];
    const float* value = (const float*)d_in[2];
    // d_in[3] attn_mask: causal by construction, handled analytically.
    const float* Wq  = (const float*)d_in[4];  const float* bq  = (const float*)d_in[5];
    const float* Wk  = (const float*)d_in[6];  const float* bk  = (const float*)d_in[7];
    const float* Wv  = (const float*)d_in[8];  const float* bv  = (const float*)d_in[9];
    const float* Wu  = (const float*)d_in[10]; const float* bu  = (const float*)d_in[11];
    const float* Wf2 = (const float*)d_in[12]; const float* bf2 = (const float*)d_in[13];
    const float* rel = (const float*)d_in[14];

    // Workspace (88 MiB): WTa 8 | Xbf 16 | Q(=G) 16 | K 16 | V 16 | U 16
    // WTb (Wu^T) borrows the V slot during the QU phase (V written later).
    char* ws = (char*)d_ws;
    const size_t WBYTES = (size_t)HDIM * HDIM * 2;   // 8 MiB
    const size_t ABYTES = (size_t)4096 * HDIM * 2;   // 16 MiB
    u16* WTa  = (u16*)ws;
    u16* Xbf  = (u16*)(ws + WBYTES);
    u16* Qbuf = (u16*)(ws + WBYTES + 1 * ABYTES);
    u16* Kbuf = (u16*)(ws + WBYTES + 2 * ABYTES);
    u16* Vbuf = (u16*)(ws + WBYTES + 3 * ABYTES);
    u16* Ubuf = (u16*)(ws + WBYTES + 4 * ABYTES);
    u16* WTb  = Vbuf;          // borrowed: freed before V GEMM writes Vbuf
    u16* Gbuf = Qbuf;          // attn reads its own Q rows, then writes them as G
    u16* VTg  = Xbf;           // free after V GEMM; reused for transposed V

    dim3 tpb(256);
    dim3 tgrid(32, 32);        // W transpose tiles
    dim3 vgrid(32, 64);        // V transpose
    const int n8 = 4096 * HDIM / 8;
    const size_t GLDS  = 65536;  // 64 KiB for gemm128
    const size_t G8LDS = 131072; // 128 KiB for gemm256_8p
    const size_t ALDS  = 71680;  // 70 KiB for attn_fused

    f32_to_bf16<<<2048, tpb, 0, stream>>>(query, Xbf, n8);
    transpose_w<<<tgrid, tpb, 0, stream>>>(Wq, WTa);
    transpose_w<<<tgrid, tpb, 0, stream>>>(Wu, WTb);
    gemm256_8p<<<256, 512, G8LDS, stream>>>(Xbf, WTa, WTb, bq, bu, Qbuf, Ubuf);
    transpose_w<<<tgrid, tpb, 0, stream>>>(Wk, WTa);
    f32_to_bf16<<<2048, tpb, 0, stream>>>(key_, Xbf, n8);
    gemm128<<<512, tpb, GLDS, stream>>>(Xbf, WTa, bk, Kbuf, 0);
    transpose_w<<<tgrid, tpb, 0, stream>>>(Wv, WTa);
    f32_to_bf16<<<2048, tpb, 0, stream>>>(value, Xbf, n8);
    gemm128<<<512, tpb, GLDS, stream>>>(Xbf, WTa, bv, Vbuf, 0);
    transpose_v<<<vgrid, tpb, 0, stream>>>(Vbuf, VTg);
    attn_fused<<<512, tpb, ALDS, stream>>>(Qbuf, Kbuf, VTg, Ubuf, rel, Gbuf);
    transpose_w<<<tgrid, tpb, 0, stream>>>(Wf2, WTa);
    gemm128<<<512, tpb, GLDS, stream>>>(Gbuf, WTa, bf2, d_out, 1);
}

// Round 17
// 330.636 us; speedup vs baseline: 1.6317x; 1.0886x over previous
//
#include <hip/hip_runtime.h>
#include <stdint.h>

// Problem constants (B=4, S=1024, H=2048, NH=16, HD=128)
#define HDIM 2048
#define SEQLEN 1024
#define NHEADS 16
#define HEADD 128

typedef unsigned short u16;
typedef unsigned int u32;
typedef __attribute__((ext_vector_type(8))) short bf16x8;   // MFMA A/B frag
typedef __attribute__((ext_vector_type(8))) u16 u16x8;
typedef __attribute__((ext_vector_type(4))) u16 u16x4;
typedef __attribute__((ext_vector_type(4))) float f32x4;

__device__ __forceinline__ float bf2f(u16 u) {
    union { u32 i; float f; } v; v.i = ((u32)u) << 16; return v.f;
}
__device__ __forceinline__ u16 f2bf(float f) {
    union { float f; u32 i; } v; v.f = f;
    return (u16)((v.i + 0x7fffu + ((v.i >> 16) & 1u)) >> 16);  // RNE
}
__device__ __forceinline__ u16 f2bf_t(float f) {               // truncation (1 op)
    union { float f; u32 i; } v; v.f = f; return (u16)(v.i >> 16);
}
// Fast silu: x * rcp(1+exp(-x)).
__device__ __forceinline__ float silu_f(float x) {
    return x * __builtin_amdgcn_rcpf(1.f + __expf(-x));
}
// Async global->LDS, 16B per lane. LDS dest = wave-uniform base + lane*16.
__device__ __forceinline__ void glds16(const void* g, void* l) {
    __builtin_amdgcn_global_load_lds(
        (const __attribute__((address_space(1))) u32*)g,
        (__attribute__((address_space(3))) u32*)l, 16, 0, 0);
}

// ---------------------------------------------------------------------------
// f32 -> bf16 bulk convert (8 elems/thread/iter), n8 = n/8.
__global__ __launch_bounds__(256) void f32_to_bf16(const float* __restrict__ in,
                                                   u16* __restrict__ out, int n8) {
    int i = blockIdx.x * 256 + threadIdx.x;
    const int stride = gridDim.x * 256;
    for (; i < n8; i += stride) {
        f32x4 a = *(const f32x4*)&in[(size_t)i * 8];
        f32x4 b = *(const f32x4*)&in[(size_t)i * 8 + 4];
        u16x8 o;
#pragma unroll
        for (int j = 0; j < 4; ++j) { o[j] = f2bf(a[j]); o[4 + j] = f2bf(b[j]); }
        *(u16x8*)&out[(size_t)i * 8] = o;
    }
}

// ---------------------------------------------------------------------------
// Transpose + downconvert W[k][n] (2048x2048 f32) -> WT[n][k] bf16.
// Write phase: 8 consecutive lanes cover 8 consecutive 16B k-chunks of one
// n-row -> 128B contiguous per lane-group (was 16B per 4KB: 8x write amp).
__global__ __launch_bounds__(256) void transpose_w(const float* __restrict__ W,
                                                   u16* __restrict__ WT) {
    __shared__ u16 T[64][76];   // 152B rows: 8B aligned, 4-way max on reads
    const int r0 = blockIdx.y * 64;   // k
    const int c0 = blockIdx.x * 64;   // n
    const int t = threadIdx.x;
#pragma unroll
    for (int c = t; c < 1024; c += 256) {
        const int r = c >> 4, cc = (c & 15) << 2;
        f32x4 v = *(const f32x4*)&W[(size_t)(r0 + r) * HDIM + c0 + cc];
        u16x4 o;
#pragma unroll
        for (int j = 0; j < 4; ++j) o[j] = f2bf(v[j]);
        *(u16x4*)&T[r][cc] = o;
    }
    __syncthreads();
#pragma unroll
    for (int c = t; c < 512; c += 256) {
        const int n = c >> 3, kc = (c & 7) << 3;   // lanes 0-7: same n, kc 0..56
        u16x8 v;
#pragma unroll
        for (int j = 0; j < 8; ++j) v[j] = T[kc + j][n];
        *(u16x8*)&WT[(size_t)(c0 + n) * HDIM + r0 + kc] = v;
    }
}

// ---------------------------------------------------------------------------
// Transpose V: Vbuf[b*1024+s][h*128+d] bf16 -> VTg[(bh*128+d)*1024+s] bf16.
// Same coalesced-write fix as transpose_w.
__global__ __launch_bounds__(256) void transpose_v(const u16* __restrict__ V,
                                                   u16* __restrict__ VT) {
    __shared__ u16 T[64][76];
    const int bh = blockIdx.y;
    const int st = (blockIdx.x & 15) * 64;
    const int dt = (blockIdx.x >> 4) * 64;
    const int b = bh >> 4, h = bh & 15;
    const int t = threadIdx.x;
#pragma unroll
    for (int c = t; c < 1024; c += 256) {        // u16x4 loads (8B, aligned)
        const int s = c >> 4, d4 = (c & 15) << 2;
        *(u16x4*)&T[s][d4] =
            *(const u16x4*)&V[(size_t)(b * SEQLEN + st + s) * HDIM + h * HEADD + dt + d4];
    }
    __syncthreads();
#pragma unroll
    for (int c = t; c < 512; c += 256) {
        const int d = c >> 3, s8 = (c & 7) << 3;  // lanes 0-7: same d, s8 0..56
        u16x8 v;
#pragma unroll
        for (int j = 0; j < 8; ++j) v[j] = T[s8 + j][d];
        *(u16x8*)&VT[((size_t)bh * HEADD + dt + d) * SEQLEN + st + s8] = v;
    }
}

// ---------------------------------------------------------------------------
// 8-phase 256x256 GEMM, QU-fused (round-16 pipeline, coalesced epilogue).
__global__ __launch_bounds__(512, 2) void gemm256_8p(
    const u16* __restrict__ X,
    const u16* __restrict__ WTq, const u16* __restrict__ WTu,
    const float* __restrict__ bq, const float* __restrict__ bu,
    u16* __restrict__ Qo, u16* __restrict__ Uo)
{
    extern __shared__ u16 lds[];   // 2 bufs x 32768 u16 (A @0, B @16384)
    const int t = threadIdx.x;
    const int lane = t & 63, wid = t >> 6;        // 8 waves
    const int l15 = lane & 15, l4 = lane >> 4;
    const int wr = wid >> 2, wn = wid & 3;        // 2M x 4N

    const int bid = blockIdx.x;                   // 256 blocks
    const int u = (bid & 7) * 32 + (bid >> 3);    // XCD-bijective
    const int tm = u & 15, tn = u >> 4;
    const int m0 = tm * 256;
    const int n0 = tn * 256;                      // 0..4095
    const u16* WT = (n0 < 2048) ? WTq : WTu;
    const float* bias = (n0 < 2048) ? bq : bu;
    u16* outp = (n0 < 2048) ? Qo : Uo;
    const int nc0 = n0 & 2047;

    const int r64 = t >> 3;                       // 0..63
    const int cse = (((t & 7) ^ (r64 & 7)) << 3);
    const u16* gA = X + (size_t)(m0 + r64) * HDIM + cse;
    const int rB0 = (r64 >> 5) * 64 + (r64 & 31);
    const u16* gB = WT + (size_t)(nc0 + rB0) * HDIM + cse;

    const int wbase = wid * 512;
    const int dstBw = (wid >> 2) * 4096 + (wid & 3) * 512;

    int offA[8][2], offB[4][2];
#pragma unroll
    for (int mf = 0; mf < 8; ++mf) {
        const int row = wr * 128 + mf * 16 + l15;
#pragma unroll
        for (int kk = 0; kk < 2; ++kk) {
            const int c = kk * 4 + l4;
            offA[mf][kk] = row * 64 + (((c) ^ (row & 7)) << 3);
        }
    }
#pragma unroll
    for (int nf = 0; nf < 4; ++nf) {
        const int row = wn * 64 + nf * 16 + l15;
#pragma unroll
        for (int kk = 0; kk < 2; ++kk) {
            const int c = kk * 4 + l4;
            offB[nf][kk] = 16384 + row * 64 + (((c) ^ (row & 7)) << 3);
        }
    }

#define SA(buf, rb, kt) glds16(gA + (size_t)(rb) * HDIM + (kt) * 64, \
                               lds + (buf) * 32768 + (rb) * 64 + wbase)
#define SB(buf, c, half, kt) glds16(gB + (size_t)((c) * 128 + (half) * 32) * HDIM + (kt) * 64, \
                               lds + (buf) * 32768 + 16384 + dstBw + (c) * 8192 + (half) * 2048)

    SA(0, 0, 0);    SA(0, 128, 0);
    SB(0, 0, 0, 0); SB(0, 1, 0, 0);
    SB(0, 0, 1, 0); SB(0, 1, 1, 0);
    SA(0, 64, 0);   SA(0, 192, 0);
    asm volatile("s_waitcnt vmcnt(4)" ::: "memory");
    __builtin_amdgcn_s_barrier();

    f32x4 acc[8][4] = {};
    int cur = 0;

#pragma unroll 1
    for (int kt = 0; kt < 32; ++kt) {
        const u16* pc = lds + cur * 32768;
        const int nb = cur ^ 1;
        const bool pf = (kt + 1 < 32);
        bf16x8 a[4][2], b0[2][2], b1[2][2];

        // ---- P1 ----
#pragma unroll
        for (int mf = 0; mf < 4; ++mf)
#pragma unroll
            for (int kk = 0; kk < 2; ++kk)
                a[mf][kk] = *(const bf16x8*)(pc + offA[mf][kk]);
#pragma unroll
        for (int nf = 0; nf < 2; ++nf)
#pragma unroll
            for (int kk = 0; kk < 2; ++kk)
                b0[nf][kk] = *(const bf16x8*)(pc + offB[nf][kk]);
        if (pf) { SA(nb, 0, kt + 1); SA(nb, 128, kt + 1); }
        __builtin_amdgcn_s_barrier();
        asm volatile("s_waitcnt lgkmcnt(0)");
        __builtin_amdgcn_sched_barrier(0);
        __builtin_amdgcn_s_setprio(1);
#pragma unroll
        for (int mf = 0; mf < 4; ++mf)
#pragma unroll
            for (int nf = 0; nf < 2; ++nf)
#pragma unroll
                for (int kk = 0; kk < 2; ++kk)
                    acc[mf][nf] = __builtin_amdgcn_mfma_f32_16x16x32_bf16(
                        a[mf][kk], b0[nf][kk], acc[mf][nf], 0, 0, 0);
        __builtin_amdgcn_s_setprio(0);
        if (pf) { asm volatile("s_waitcnt vmcnt(4)" ::: "memory"); }
        else    { asm volatile("s_waitcnt vmcnt(2)" ::: "memory"); }
        __builtin_amdgcn_s_barrier();

        // ---- P2 ----
#pragma unroll
        for (int nf = 0; nf < 2; ++nf)
#pragma unroll
            for (int kk = 0; kk < 2; ++kk)
                b1[nf][kk] = *(const bf16x8*)(pc + offB[2 + nf][kk]);
        if (pf) { SB(nb, 0, 0, kt + 1); SB(nb, 1, 0, kt + 1); }
        __builtin_amdgcn_s_barrier();
        asm volatile("s_waitcnt lgkmcnt(0)");
        __builtin_amdgcn_sched_barrier(0);
        __builtin_amdgcn_s_setprio(1);
#pragma unroll
        for (int mf = 0; mf < 4; ++mf)
#pragma unroll
            for (int nf = 0; nf < 2; ++nf)
#pragma unroll
                for (int kk = 0; kk < 2; ++kk)
                    acc[mf][2 + nf] = __builtin_amdgcn_mfma_f32_16x16x32_bf16(
                        a[mf][kk], b1[nf][kk], acc[mf][2 + nf], 0, 0, 0);
        __builtin_amdgcn_s_setprio(0);
        if (pf) { asm volatile("s_waitcnt vmcnt(4)" ::: "memory"); }
        else    { asm volatile("s_waitcnt vmcnt(0)" ::: "memory"); }
        __builtin_amdgcn_s_barrier();

        // ---- P3 ----
#pragma unroll
        for (int mf = 0; mf < 4; ++mf)
#pragma unroll
            for (int kk = 0; kk < 2; ++kk)
                a[mf][kk] = *(const bf16x8*)(pc + offA[4 + mf][kk]);
        if (pf) { SB(nb, 0, 1, kt + 1); SB(nb, 1, 1, kt + 1); }
        __builtin_amdgcn_s_barrier();
        asm volatile("s_waitcnt lgkmcnt(0)");
        __builtin_amdgcn_sched_barrier(0);
        __builtin_amdgcn_s_setprio(1);
#pragma unroll
        for (int mf = 0; mf < 4; ++mf)
#pragma unroll
            for (int nf = 0; nf < 2; ++nf)
#pragma unroll
                for (int kk = 0; kk < 2; ++kk)
                    acc[4 + mf][nf] = __builtin_amdgcn_mfma_f32_16x16x32_bf16(
                        a[mf][kk], b0[nf][kk], acc[4 + mf][nf], 0, 0, 0);
        __builtin_amdgcn_s_setprio(0);
        __builtin_amdgcn_s_barrier();

        // ---- P4 ----
        if (pf) { SA(nb, 64, kt + 1); SA(nb, 192, kt + 1); }
        __builtin_amdgcn_s_barrier();
        __builtin_amdgcn_s_setprio(1);
#pragma unroll
        for (int mf = 0; mf < 4; ++mf)
#pragma unroll
            for (int nf = 0; nf < 2; ++nf)
#pragma unroll
                for (int kk = 0; kk < 2; ++kk)
                    acc[4 + mf][2 + nf] = __builtin_amdgcn_mfma_f32_16x16x32_bf16(
                        a[mf][kk], b1[nf][kk], acc[4 + mf][2 + nf], 0, 0, 0);
        __builtin_amdgcn_s_setprio(0);
        if (pf) { asm volatile("s_waitcnt vmcnt(4)" ::: "memory"); }
        __builtin_amdgcn_s_barrier();
        cur ^= 1;
    }
#undef SA
#undef SB

    // Coalesced epilogue: per row, sweep the 4 nf chunks back-to-back.
    float bvv[4];
#pragma unroll
    for (int nf = 0; nf < 4; ++nf) bvv[nf] = bias[nc0 + wn * 64 + nf * 16 + l15];
#pragma unroll
    for (int mf = 0; mf < 8; ++mf) {
        const int mbase = m0 + wr * 128 + mf * 16 + (l4 << 2);
#pragma unroll
        for (int r = 0; r < 4; ++r) {
            u16* rowp = outp + (size_t)(mbase + r) * HDIM + nc0 + wn * 64 + l15;
#pragma unroll
            for (int nf = 0; nf < 4; ++nf)
                rowp[nf * 16] = f2bf(silu_f(acc[mf][nf][r] + bvv[nf]));
        }
    }
}

// ---------------------------------------------------------------------------
// Pipelined GEMM 128x128 (round-15 pipeline, coalesced epilogue).
__global__ __launch_bounds__(256) void gemm128(
    const u16* __restrict__ X, const u16* __restrict__ WT,
    const float* __restrict__ bias, void* __restrict__ outp, const int mode)
{
    extern __shared__ u16 lds[];   // 2 bufs x (A 8192 + B 8192) u16 = 64 KiB
    const int t = threadIdx.x;
    const int lane = t & 63, wid = t >> 6;       // 4 waves
    const int l15 = lane & 15, l4 = lane >> 4;
    const int wr = wid >> 1, wn = wid & 1;

    const int bid = blockIdx.x;                  // 512 blocks
    const int u = (bid & 7) * 64 + (bid >> 3);   // XCD-bijective
    const int tm = u & 31, tn = u >> 5;
    const int m0 = tm * 128, n0 = tn * 128;

    const int ric = t >> 3;
    const int cse = (((t & 7) ^ (ric & 7)) << 3);
    const u16* gA = X  + (size_t)(m0 + ric) * HDIM + cse;
    const u16* gB = WT + (size_t)(n0 + ric) * HDIM + cse;

    u16* buf0 = lds;
    u16* buf1 = lds + 16384;
    const int wbase = wid * 512;

    int offA[4][2], offB[4][2];
#pragma unroll
    for (int i = 0; i < 4; ++i) {
        const int row = wr * 64 + i * 16 + l15;
#pragma unroll
        for (int kk = 0; kk < 2; ++kk)
            offA[i][kk] = ((row * 128 + kk * 64 + l4 * 16) ^ ((row & 7) << 4)) >> 1;
    }
#pragma unroll
    for (int j = 0; j < 4; ++j) {
        const int row = wn * 64 + j * 16 + l15;
#pragma unroll
        for (int kk = 0; kk < 2; ++kk)
            offB[j][kk] = 8192 + ((((row * 128 + kk * 64 + l4 * 16) ^ ((row & 7) << 4))) >> 1);
    }

#define STAGE_A(buf, c, kt) glds16(gA + (size_t)(c) * 32 * HDIM + (kt) * 64, (buf) + (c) * 2048 + wbase)
#define STAGE_B(buf, c, kt) glds16(gB + (size_t)(c) * 32 * HDIM + (kt) * 64, (buf) + 8192 + (c) * 2048 + wbase)

    STAGE_B(buf0, 0, 0); STAGE_B(buf0, 1, 0); STAGE_B(buf0, 2, 0); STAGE_B(buf0, 3, 0);
    STAGE_A(buf0, 0, 0); STAGE_A(buf0, 1, 0); STAGE_A(buf0, 2, 0); STAGE_A(buf0, 3, 0);
    STAGE_B(buf1, 0, 1); STAGE_B(buf1, 1, 1); STAGE_B(buf1, 2, 1); STAGE_B(buf1, 3, 1);
    STAGE_A(buf1, 0, 1); STAGE_A(buf1, 2, 1);
    asm volatile("s_waitcnt vmcnt(6)" ::: "memory");
    __builtin_amdgcn_s_barrier();

    f32x4 acc[4][4] = {};
    u16* pc = buf0;
    u16* pn = buf1;

#pragma unroll 1
    for (int tt = 0; tt < 32; ++tt) {
        bf16x8 bfr[4][2], afr[2][2];
#pragma unroll
        for (int j = 0; j < 4; ++j)
#pragma unroll
            for (int kk = 0; kk < 2; ++kk)
                bfr[j][kk] = *(const bf16x8*)(pc + offB[j][kk]);
#pragma unroll
        for (int i = 0; i < 2; ++i)
#pragma unroll
            for (int kk = 0; kk < 2; ++kk)
                afr[i][kk] = *(const bf16x8*)(pc + offA[i][kk]);
        if (tt + 1 < 32) { STAGE_A(pn, 1, tt + 1); STAGE_A(pn, 3, tt + 1); }
        __builtin_amdgcn_s_barrier();
        asm volatile("s_waitcnt lgkmcnt(0)");
        __builtin_amdgcn_sched_barrier(0);
        __builtin_amdgcn_s_setprio(1);
#pragma unroll
        for (int i = 0; i < 2; ++i)
#pragma unroll
            for (int j = 0; j < 4; ++j)
#pragma unroll
                for (int kk = 0; kk < 2; ++kk)
                    acc[i][j] = __builtin_amdgcn_mfma_f32_16x16x32_bf16(
                        afr[i][kk], bfr[j][kk], acc[i][j], 0, 0, 0);
        __builtin_amdgcn_s_setprio(0);
        __builtin_amdgcn_s_barrier();

#pragma unroll
        for (int i = 0; i < 2; ++i)
#pragma unroll
            for (int kk = 0; kk < 2; ++kk)
                afr[i][kk] = *(const bf16x8*)(pc + offA[2 + i][kk]);
        if (tt + 2 < 32) {
            STAGE_B(pc, 0, tt + 2); STAGE_B(pc, 1, tt + 2);
            STAGE_B(pc, 2, tt + 2); STAGE_B(pc, 3, tt + 2);
            STAGE_A(pc, 0, tt + 2); STAGE_A(pc, 2, tt + 2);
        }
        __builtin_amdgcn_s_barrier();
        asm volatile("s_waitcnt lgkmcnt(0)");
        __builtin_amdgcn_sched_barrier(0);
        __builtin_amdgcn_s_setprio(1);
#pragma unroll
        for (int i = 0; i < 2; ++i)
#pragma unroll
            for (int j = 0; j < 4; ++j)
#pragma unroll
                for (int kk = 0; kk < 2; ++kk)
                    acc[2 + i][j] = __builtin_amdgcn_mfma_f32_16x16x32_bf16(
                        afr[i][kk], bfr[j][kk], acc[2 + i][j], 0, 0, 0);
        __builtin_amdgcn_s_setprio(0);
        if (tt + 2 < 32)      { asm volatile("s_waitcnt vmcnt(6)" ::: "memory"); }
        else if (tt + 1 < 32) { asm volatile("s_waitcnt vmcnt(0)" ::: "memory"); }
        __builtin_amdgcn_s_barrier();
        u16* tmp = pc; pc = pn; pn = tmp;
    }
#undef STAGE_A
#undef STAGE_B

    // Coalesced epilogue: per row, sweep the 4 j chunks back-to-back.
    float bvv[4];
#pragma unroll
    for (int j = 0; j < 4; ++j) bvv[j] = bias[n0 + wn * 64 + j * 16 + l15];
#pragma unroll
    for (int i = 0; i < 4; ++i) {
        const int mbase = m0 + wr * 64 + i * 16 + (l4 << 2);
#pragma unroll
        for (int r = 0; r < 4; ++r) {
            const size_t rowoff = (size_t)(mbase + r) * HDIM + n0 + wn * 64 + l15;
#pragma unroll
            for (int j = 0; j < 4; ++j) {
                const float v = acc[i][j][r] + bvv[j];
                if (mode == 0)
                    ((u16*)outp)[rowoff + j * 16] = f2bf(silu_f(v));
                else
                    ((float*)outp)[rowoff + j * 16] = v;
            }
        }
    }
}

// ---------------------------------------------------------------------------
// Fused SiLU-attention + gating (round-15 structure; coalesced G-write).
__global__ __launch_bounds__(256) void attn_fused(
    const u16* __restrict__ Qb, const u16* __restrict__ Kb,
    const u16* __restrict__ VTg, const u16* __restrict__ Ub,
    const float* __restrict__ rel, u16* __restrict__ G)
{
    extern __shared__ u16 alds[];
    u16* Ps = alds + 24576;
    float* relh = (float*)(alds + 33792);

    const int idx = blockIdx.x;
    const int bh8 = idx & 7;
    const int j = (idx >> 3) & 7;
    const int bhhi = idx >> 6;            // 0..7
    const int bh = bhhi * 8 + bh8;
    const int b = bh >> 4, h = bh & 15;
    const int qS0 = j * 64;               // short subtile
    const int qL0 = (15 - j) * 64;        // long subtile
    const int nkt = 16 - j;
    const int t = threadIdx.x, lane = t & 63, w = t >> 6;
    const int l15 = lane & 15, l4 = lane >> 4;
    const size_t rowbase = (size_t)b * SEQLEN;
    const int col0 = h * HEADD;
    const float scale = 0.088388347648318447f;   // 1/sqrt(128)

    for (int i = t; i < 1024; i += 256) relh[i] = rel[(size_t)(1023 + i) * NHEADS + h];

    const int rK = t >> 4;
    const int cK = (t & 15) ^ (rK & 7);
    const u16* gK = Kb + (rowbase + rK) * HDIM + col0 + cK * 8;
    const int rV = t >> 3;
    const int cV = (t & 7) ^ (rV & 7);
    const u16* gV = VTg + ((size_t)bh * HEADD + rV) * SEQLEN + cV * 8;
    const int sdst = w * 512;

    bf16x8 aqL[4], aqS[4];
    {
        const int qrowL = qL0 + w * 16 + l15;
        const int qrowS = qS0 + w * 16 + l15;
#pragma unroll
        for (int dc = 0; dc < 4; ++dc) {
            aqL[dc] = *(const bf16x8*)&Qb[(rowbase + qrowL) * HDIM + col0 + dc * 32 + (l4 << 3)];
            aqS[dc] = *(const bf16x8*)&Qb[(rowbase + qrowS) * HDIM + col0 + dc * 32 + (l4 << 3)];
        }
    }

    f32x4 oaccL[8] = {}, oaccS[8] = {};

#define STAGE_K(kt) do {                                                        \
    const size_t ko_ = (size_t)(kt) * 64;                                       \
    _Pragma("unroll") for (int c = 0; c < 4; ++c)                               \
        glds16(gK + (ko_ + c * 16) * HDIM, alds + c * 2048 + sdst);             \
} while (0)
#define STAGE_V(kt, bsel) do {                                                  \
    u16* vb_ = alds + 8192 + ((bsel) ? 8192 : 0);                               \
    const size_t ko_ = (size_t)(kt) * 64;                                       \
    _Pragma("unroll") for (int c = 0; c < 4; ++c)                               \
        glds16(gV + (size_t)c * 32 * SEQLEN + ko_, vb_ + c * 2048 + sdst);      \
} while (0)

    STAGE_K(0); STAGE_V(0, 0);
    asm volatile("s_waitcnt vmcnt(0)" ::: "memory");
    __builtin_amdgcn_s_barrier();

    int cur = 0;
#pragma unroll 1
    for (int kt = 0; kt < nkt; ++kt) {
        const int k0 = kt * 64;
        const bool doS = (kt <= j);               // block-uniform
        if (kt + 1 < nkt) STAGE_V(kt + 1, cur ^ 1);
        const u16* kb = alds;
        const u16* vb = alds + 8192 + (cur ? 8192 : 0);

#pragma unroll
        for (int kf = 0; kf < 4; ++kf) {
            const int krow = kf * 16 + l15;
            f32x4 sL = {}, sS = {};
            __builtin_amdgcn_s_setprio(1);
#pragma unroll
            for (int dc = 0; dc < 4; ++dc) {
                bf16x8 bk = *(const bf16x8*)&kb[krow * 128 + (((dc * 4 + l4) ^ (krow & 7)) << 3)];
                sL = __builtin_amdgcn_mfma_f32_16x16x32_bf16(aqL[dc], bk, sL, 0, 0, 0);
                if (doS) sS = __builtin_amdgcn_mfma_f32_16x16x32_bf16(aqS[dc], bk, sS, 0, 0, 0);
            }
            __builtin_amdgcn_s_setprio(0);
            const int kabs = k0 + krow;
            const int prow = w * 16 + (l4 << 2);
#pragma unroll
            for (int r = 0; r < 4; ++r) {
                const int qabsL = qL0 + prow + r;
                float vL = 0.f;
                if (kabs <= qabsL) vL = silu_f(fmaf(sL[r], scale, relh[qabsL - kabs]));
                Ps[(prow + r) * 72 + kf * 16 + l15] = f2bf_t(vL);
            }
            if (doS) {
#pragma unroll
                for (int r = 0; r < 4; ++r) {
                    const int qabsS = qS0 + prow + r;
                    float vS = 0.f;
                    if (kabs <= qabsS) vS = silu_f(fmaf(sS[r], scale, relh[qabsS - kabs]));
                    Ps[(64 + prow + r) * 72 + kf * 16 + l15] = f2bf_t(vS);
                }
            }
        }
        asm volatile("s_waitcnt lgkmcnt(0)" ::: "memory");
        __builtin_amdgcn_s_barrier();                 // Kbuf free
        if (kt + 1 < nkt) STAGE_K(kt + 1);

        bf16x8 apL[2], apS[2];
#pragma unroll
        for (int kc = 0; kc < 2; ++kc) {
            apL[kc] = *(const bf16x8*)&Ps[(w * 16 + l15) * 72 + kc * 32 + (l4 << 3)];
            if (doS) apS[kc] = *(const bf16x8*)&Ps[(64 + w * 16 + l15) * 72 + kc * 32 + (l4 << 3)];
        }
        __builtin_amdgcn_s_setprio(1);
#pragma unroll
        for (int df = 0; df < 8; ++df) {
            const int vrow = df * 16 + l15;
#pragma unroll
            for (int kc = 0; kc < 2; ++kc) {
                bf16x8 bv = *(const bf16x8*)&vb[vrow * 64 + (((kc * 4 + l4) ^ (vrow & 7)) << 3)];
                oaccL[df] = __builtin_amdgcn_mfma_f32_16x16x32_bf16(apL[kc], bv, oaccL[df], 0, 0, 0);
                if (doS) oaccS[df] = __builtin_amdgcn_mfma_f32_16x16x32_bf16(apS[kc], bv, oaccS[df], 0, 0, 0);
            }
        }
        __builtin_amdgcn_s_setprio(0);
        asm volatile("s_waitcnt vmcnt(0) lgkmcnt(0)" ::: "memory");
        __builtin_amdgcn_s_barrier();
        cur ^= 1;
    }
#undef STAGE_K
#undef STAGE_V

    // G = O * U, row-sweep order for coalescing
#pragma unroll
    for (int r = 0; r < 4; ++r) {
        const int qr = w * 16 + (l4 << 2) + r;
        const size_t rowL = (rowbase + qL0 + qr) * HDIM + col0 + l15;
        const size_t rowS = (rowbase + qS0 + qr) * HDIM + col0 + l15;
#pragma unroll
        for (int df = 0; df < 8; ++df)
            G[rowL + df * 16] = f2bf(oaccL[df][r] * bf2f(Ub[rowL + df * 16]));
#pragma unroll
        for (int df = 0; df < 8; ++df)
            G[rowS + df * 16] = f2bf(oaccS[df][r] * bf2f(Ub[rowS + df * 16]));
    }
}

// ---------------------------------------------------------------------------
extern "C" void kernel_launch(void* const* d_in, const int* in_sizes, int n_in,
                              void* d_out, int out_size, void* d_ws, size_t ws_size,
                              hipStream_t stream) {
    const float* query = (const float*)d_in[0];
    const float* key_  = (const float*)d_in[1];
    const float* value = (const float*)d_in[2];
    // d_in[3] attn_mask: causal by construction, handled analytically.
    const float* Wq  = (const float*)d_in[4];  const float* bq  = (const float*)d_in[5];
    const float* Wk  = (const float*)d_in[6];  const float* bk  = (const float*)d_in[7];
    const float* Wv  = (const float*)d_in[8];  const float* bv  = (const float*)d_in[9];
    const float* Wu  = (const float*)d_in[10]; const float* bu  = (const float*)d_in[11];
    const float* Wf2 = (const float*)d_in[12]; const float* bf2 = (const float*)d_in[13];
    const float* rel = (const float*)d_in[14];

    // Workspace (88 MiB): WTa 8 | Xbf 16 | Q(=G) 16 | K 16 | V 16 | U 16
    char* ws = (char*)d_ws;
    const size_t WBYTES = (size_t)HDIM * HDIM * 2;   // 8 MiB
    const size_t ABYTES = (size_t)4096 * HDIM * 2;   // 16 MiB
    u16* WTa  = (u16*)ws;
    u16* Xbf  = (u16*)(ws + WBYTES);
    u16* Qbuf = (u16*)(ws + WBYTES + 1 * ABYTES);
    u16* Kbuf = (u16*)(ws + WBYTES + 2 * ABYTES);
    u16* Vbuf = (u16*)(ws + WBYTES + 3 * ABYTES);
    u16* Ubuf = (u16*)(ws + WBYTES + 4 * ABYTES);
    u16* WTb  = Vbuf;          // borrowed: freed before V GEMM writes Vbuf
    u16* Gbuf = Qbuf;          // attn reads its own Q rows, then writes them as G
    u16* VTg  = Xbf;           // free after V GEMM; reused for transposed V

    dim3 tpb(256);
    dim3 tgrid(32, 32);        // W transpose tiles
    dim3 vgrid(32, 64);        // V transpose
    const int n8 = 4096 * HDIM / 8;
    const size_t GLDS  = 65536;  // 64 KiB for gemm128
    const size_t G8LDS = 131072; // 128 KiB for gemm256_8p
    const size_t ALDS  = 71680;  // 70 KiB for attn_fused

    f32_to_bf16<<<2048, tpb, 0, stream>>>(query, Xbf, n8);
    transpose_w<<<tgrid, tpb, 0, stream>>>(Wq, WTa);
    transpose_w<<<tgrid, tpb, 0, stream>>>(Wu, WTb);
    gemm256_8p<<<256, 512, G8LDS, stream>>>(Xbf, WTa, WTb, bq, bu, Qbuf, Ubuf);
    transpose_w<<<tgrid, tpb, 0, stream>>>(Wk, WTa);
    f32_to_bf16<<<2048, tpb, 0, stream>>>(key_, Xbf, n8);
    gemm128<<<512, tpb, GLDS, stream>>>(Xbf, WTa, bk, Kbuf, 0);
    transpose_w<<<tgrid, tpb, 0, stream>>>(Wv, WTa);
    f32_to_bf16<<<2048, tpb, 0, stream>>>(value, Xbf, n8);
    gemm128<<<512, tpb, GLDS, stream>>>(Xbf, WTa, bv, Vbuf, 0);
    transpose_v<<<vgrid, tpb, 0, stream>>>(Vbuf, VTg);
    attn_fused<<<512, tpb, ALDS, stream>>>(Qbuf, Kbuf, VTg, Ubuf, rel, Gbuf);
    transpose_w<<<tgrid, tpb, 0, stream>>>(Wf2, WTa);
    gemm128<<<512, tpb, GLDS, stream>>>(Gbuf, WTa, bf2, d_out, 1);
}